// Round 2
// baseline (606.691 us; speedup 1.0000x reference)
//
#include <hip/hip_runtime.h>
#include <hip/hip_bf16.h>
#include <math.h>

// Problem constants
#define T_LEN   4096
#define D_DIM   512
#define H_NUM   8
#define HD_DIM  64
#define W_WIN   32
#define HID_DIM 1536
#define M_ROWS  8192   // B*T

typedef __hip_bfloat16 bf16;
typedef __bf16  bf16x8 __attribute__((ext_vector_type(8)));
typedef float   f32x4  __attribute__((ext_vector_type(4)));

__device__ __forceinline__ float b2f(bf16 x) { return __bfloat162float(x); }
__device__ __forceinline__ bf16  f2b(float x){ return __float2bfloat16(x); }

// Read element i of a parameter tensor whose dtype is f32 (flag) or bf16.
__device__ __forceinline__ float rdP(const void* p, int i, bool f32) {
  return f32 ? ((const float*)p)[i] : b2f(((const bf16*)p)[i]);
}

__device__ __forceinline__ float wave_reduce_sum(float v) {
  #pragma unroll
  for (int off = 32; off; off >>= 1) v += __shfl_xor(v, off, 64);
  return v;
}

// ---------------------------------------------------------------------------
// Input-dtype detector. For bf16-packed data the low 16 bits of each dword
// are a valid bf16 of ~N(0,1) scale (exponent field in ~[117,129]); for f32
// data those bits are uniform mantissa noise. Vote over 256 dwords of x.
// flag = 1 -> inputs are float32.
// ---------------------------------------------------------------------------
__global__ void detect_kernel(const unsigned* __restrict__ x, int* flag) {
  if (threadIdx.x == 0 && blockIdx.x == 0) {
    int votes = 0;
    for (int i = 0; i < 256; ++i) {
      unsigned e = (x[i] >> 7) & 0xffu;       // exponent field of low half
      if (e >= 90u && e <= 140u) ++votes;
    }
    *flag = (votes < 200) ? 1 : 0;
  }
}

// ---------------------------------------------------------------------------
// LayerNorm. mode 0: out = LN(in)*g+b.  mode 1: additionally multiply by
// (1 + amp*sin(t*freqs[d]+phases[d])) with t = row % T.  In-place safe.
// in dtype: bf16, or f32 if (flag && in_follows). out likewise.
// g/b/freqs/phases/amp always follow the flag (they are harness inputs).
// ---------------------------------------------------------------------------
__global__ __launch_bounds__(256) void ln_kernel(
    const void* __restrict__ in, const void* __restrict__ g, const void* __restrict__ bb,
    void* __restrict__ out, int mode,
    const void* __restrict__ freqs, const void* __restrict__ phases,
    const void* __restrict__ amp,
    const int* __restrict__ flag, int in_follows, int out_follows)
{
  bool f32  = (*flag != 0);
  bool inF  = f32 && (in_follows != 0);
  bool outF = f32 && (out_follows != 0);

  int wave = threadIdx.x >> 6;
  int lane = threadIdx.x & 63;
  int row  = blockIdx.x * 4 + wave;

  float x[8];
  if (inF) {
    const float* rp = (const float*)in + (size_t)row * D_DIM + lane * 8;
    float4 v0 = *reinterpret_cast<const float4*>(rp);
    float4 v1 = *reinterpret_cast<const float4*>(rp + 4);
    x[0]=v0.x; x[1]=v0.y; x[2]=v0.z; x[3]=v0.w;
    x[4]=v1.x; x[5]=v1.y; x[6]=v1.z; x[7]=v1.w;
  } else {
    bf16x8 v = *reinterpret_cast<const bf16x8*>(
        (const bf16*)in + (size_t)row * D_DIM + lane * 8);
    #pragma unroll
    for (int i = 0; i < 8; ++i) x[i] = (float)v[i];
  }

  float s = 0.f, s2 = 0.f;
  #pragma unroll
  for (int i = 0; i < 8; ++i) { s += x[i]; s2 += x[i]*x[i]; }
  s  = wave_reduce_sum(s);
  s2 = wave_reduce_sum(s2);
  float mu   = s * (1.f / D_DIM);
  float var  = s2 * (1.f / D_DIM) - mu * mu;
  float rstd = rsqrtf(var + 1e-5f);

  int t = row & (T_LEN - 1);
  float ampf = (mode == 1) ? rdP(amp, 0, f32) : 0.f;

  float o[8];
  #pragma unroll
  for (int i = 0; i < 8; ++i) {
    int d = lane * 8 + i;
    float val = (x[i] - mu) * rstd * rdP(g, d, f32) + rdP(bb, d, f32);
    if (mode == 1) {
      float m = sinf(fmaf((float)t, rdP(freqs, d, f32), rdP(phases, d, f32)));
      val *= (1.f + ampf * m);
    }
    o[i] = val;
  }

  if (outF) {
    float* op = (float*)out + (size_t)row * D_DIM + lane * 8;
    *reinterpret_cast<float4*>(op)     = make_float4(o[0], o[1], o[2], o[3]);
    *reinterpret_cast<float4*>(op + 4) = make_float4(o[4], o[5], o[6], o[7]);
  } else {
    bf16x8 ov;
    #pragma unroll
    for (int i = 0; i < 8; ++i) ov[i] = (__bf16)o[i];
    *reinterpret_cast<bf16x8*>((bf16*)out + (size_t)row * D_DIM + lane * 8) = ov;
  }
}

// ---------------------------------------------------------------------------
// Transpose (R x C) -> (C x R). src dtype follows flag; dst always bf16.
// ---------------------------------------------------------------------------
__global__ __launch_bounds__(256) void transpose_kernel(
    const void* __restrict__ src, bf16* __restrict__ dst, int R, int C,
    const int* __restrict__ flag)
{
  bool f32 = (*flag != 0);
  __shared__ bf16 tile[32][33];
  int tx = threadIdx.x & 31;
  int ty = threadIdx.x >> 5;          // 0..7
  int c0 = blockIdx.x * 32;
  int r0 = blockIdx.y * 32;
  #pragma unroll
  for (int j = 0; j < 32; j += 8)
    tile[ty + j][tx] = f2b(rdP(src, (size_t)(r0 + ty + j) * C + c0 + tx, f32));
  __syncthreads();
  #pragma unroll
  for (int j = 0; j < 32; j += 8)
    dst[(size_t)(c0 + ty + j) * R + r0 + tx] = tile[tx][ty + j];
}

// ---------------------------------------------------------------------------
// GEMM: C[M x N] = A[M x K] * B, with Bt = B^T given as [N x K] row-major.
// All operands bf16 (internal). 128x128 block tile, 4 waves, each wave 64x64
// via 4x4 mfma 16x16x32. mode 0: C. mode 1: C + extra. mode 2: silu(extra)*C.
// ---------------------------------------------------------------------------
__global__ __launch_bounds__(256) void gemm_kernel(
    const bf16* __restrict__ A, const bf16* __restrict__ Bt,
    bf16* Cout, const bf16* extra, int N, int K, int mode)
{
  int lane = threadIdx.x & 63;
  int wid  = threadIdx.x >> 6;
  int quad = lane >> 4;
  int l16  = lane & 15;
  int mbase = blockIdx.y * 128 + (wid >> 1) * 64;
  int nbase = blockIdx.x * 128 + (wid & 1) * 64;

  f32x4 acc[4][4] = {};

  for (int k0 = 0; k0 < K; k0 += 32) {
    int kk = k0 + quad * 8;
    bf16x8 a[4], bb[4];
    #pragma unroll
    for (int i = 0; i < 4; ++i)
      a[i] = *reinterpret_cast<const bf16x8*>(A + (size_t)(mbase + i*16 + l16) * K + kk);
    #pragma unroll
    for (int j = 0; j < 4; ++j)
      bb[j] = *reinterpret_cast<const bf16x8*>(Bt + (size_t)(nbase + j*16 + l16) * K + kk);
    #pragma unroll
    for (int i = 0; i < 4; ++i)
      #pragma unroll
      for (int j = 0; j < 4; ++j)
        acc[i][j] = __builtin_amdgcn_mfma_f32_16x16x32_bf16(a[i], bb[j], acc[i][j], 0, 0, 0);
  }

  #pragma unroll
  for (int i = 0; i < 4; ++i) {
    #pragma unroll
    for (int j = 0; j < 4; ++j) {
      #pragma unroll
      for (int r = 0; r < 4; ++r) {
        int row = mbase + i * 16 + quad * 4 + r;
        int col = nbase + j * 16 + l16;
        size_t idx = (size_t)row * N + col;
        float c = acc[i][j][r];
        if (mode == 1) {
          c += b2f(extra[idx]);
        } else if (mode == 2) {
          float gg = b2f(extra[idx]);
          c *= gg / (1.f + expf(-gg));   // silu(g) * c
        }
        Cout[idx] = f2b(c);
      }
    }
  }
}

// ---------------------------------------------------------------------------
// Sliding-window sigmoid attention (all bf16 internal). One wave per
// (row, head); lane = dim. Window = strictly previous W tokens.
// ---------------------------------------------------------------------------
__global__ __launch_bounds__(256) void attn_kernel(
    const bf16* q, const bf16* __restrict__ kv, bf16* msg)
{
  int lane = threadIdx.x & 63;
  int wv   = (blockIdx.x << 2) + (threadIdx.x >> 6);
  int row  = wv >> 3;     // 0..8191
  int head = wv & 7;
  int t    = row & (T_LEN - 1);

  size_t qoff = (size_t)row * D_DIM + head * HD_DIM + lane;
  float qv = b2f(q[qoff]);
  float acc = 0.f;

  int wmax = (t < W_WIN) ? t : W_WIN;
  for (int w = 1; w <= wmax; ++w) {
    const bf16* kvrow = kv + (size_t)(row - w) * (2 * D_DIM) + head * 2 * HD_DIM;
    float p = qv * b2f(kvrow[lane]);
    p = wave_reduce_sum(p);
    float tau = 1.f / (1.f + expf(-p * 0.125f));   // sigmoid(qk / sqrt(64))
    acc += tau * b2f(kvrow[HD_DIM + lane]);
  }
  msg[qoff] = f2b(acc);
}

// ---------------------------------------------------------------------------
extern "C" void kernel_launch(void* const* d_in, const int* in_sizes, int n_in,
                              void* d_out, int out_size, void* d_ws, size_t ws_size,
                              hipStream_t stream)
{
  const void* x      = d_in[0];
  const void* pre_g  = d_in[1];
  const void* pre_b  = d_in[2];
  const void* wq     = d_in[3];
  const void* wkv    = d_in[4];
  const void* wo     = d_in[5];
  const void* attn_g = d_in[6];
  const void* attn_b = d_in[7];
  const void* freqs  = d_in[8];
  const void* phases = d_in[9];
  const void* amp    = d_in[10];
  const void* w_gate = d_in[11];
  const void* w_val  = d_in[12];
  const void* w_proj = d_in[13];
  const void* ffn_g  = d_in[14];
  const void* ffn_b  = d_in[15];

  // Workspace layout (bytes). Total ~38.5 MiB.
  char* ws = (char*)d_ws;
  int*  flag = (int*)(ws + 0);
  bf16* Btq  = (bf16*)(ws + 512);       //  512 x  512
  bf16* Btkv = (bf16*)(ws + 524800);    // 1024 x  512
  bf16* Bto  = (bf16*)(ws + 1573376);   //  512 x  512
  bf16* Btg  = (bf16*)(ws + 2097664);   // 1536 x  512
  bf16* Btv  = (bf16*)(ws + 3670528);   // 1536 x  512
  bf16* Btp  = (bf16*)(ws + 5243392);   //  512 x 1536
  bf16* h    = (bf16*)(ws + 6816256);   // 8192 x  512  (h -> s1 -> y -> u, in place)
  bf16* qb   = (bf16*)(ws + 15204864);  // 8192 x  512  (q -> msg, in place)
  bf16* kvb  = (bf16*)(ws + 23593472);  // 8192 x 1024
  bf16* gb   = qb;                      // 8192 x 1536 gate/act reuses q+kv region

  // 0. Detect input dtype (writes flag; every launch).
  detect_kernel<<<1, 64, 0, stream>>>((const unsigned*)x, flag);

  // 1. Transpose all weights to [N x K] row-major bf16.
  transpose_kernel<<<dim3(16, 16), 256, 0, stream>>>(wq,     Btq,  512,  512, flag);
  transpose_kernel<<<dim3(32, 16), 256, 0, stream>>>(wkv,    Btkv, 512, 1024, flag);
  transpose_kernel<<<dim3(16, 16), 256, 0, stream>>>(wo,     Bto,  512,  512, flag);
  transpose_kernel<<<dim3(48, 16), 256, 0, stream>>>(w_gate, Btg,  512, 1536, flag);
  transpose_kernel<<<dim3(48, 16), 256, 0, stream>>>(w_val,  Btv,  512, 1536, flag);
  transpose_kernel<<<dim3(16, 48), 256, 0, stream>>>(w_proj, Btp, 1536,  512, flag);

  // 2. h = LN(x)  (x follows flag; h is bf16)
  ln_kernel<<<2048, 256, 0, stream>>>(x, pre_g, pre_b, h, 0,
                                      nullptr, nullptr, nullptr, flag, 1, 0);

  // 3. q = h @ wq ; kv = h @ wkv
  gemm_kernel<<<dim3(4, 64),  256, 0, stream>>>(h, Btq,  qb,  nullptr,  512, 512, 0);
  gemm_kernel<<<dim3(8, 64),  256, 0, stream>>>(h, Btkv, kvb, nullptr, 1024, 512, 0);

  // 4. msg = window-attention(q, kv)   (msg overwrites q)
  attn_kernel<<<16384, 256, 0, stream>>>(qb, kvb, qb);

  // 5. s1 = h + msg @ wo   (in place over h)
  gemm_kernel<<<dim3(4, 64),  256, 0, stream>>>(qb, Bto, h, h, 512, 512, 1);

  // 6. y = LN(s1) * (1 + amp*sin(t*freqs+phases))   (in place over h, bf16)
  ln_kernel<<<2048, 256, 0, stream>>>(h, attn_g, attn_b, h, 1,
                                      freqs, phases, amp, flag, 0, 0);

  // 7. g = y @ w_gate ; act = silu(g) * (y @ w_val)   (act overwrites g)
  gemm_kernel<<<dim3(12, 64), 256, 0, stream>>>(h, Btg, gb, nullptr, 1536, 512, 0);
  gemm_kernel<<<dim3(12, 64), 256, 0, stream>>>(h, Btv, gb, gb,      1536, 512, 2);

  // 8. u = y + act @ w_proj   (in place over h)
  gemm_kernel<<<dim3(4, 64),  256, 0, stream>>>(gb, Btp, h, h, 512, 1536, 1);

  // 9. out = LN(u)  (out follows flag)
  ln_kernel<<<2048, 256, 0, stream>>>(h, ffn_g, ffn_b, d_out, 0,
                                      nullptr, nullptr, nullptr, flag, 0, 1);
}

// Round 4
// 469.150 us; speedup vs baseline: 1.2932x; 1.2932x over previous
//
#include <hip/hip_runtime.h>
#include <hip/hip_bf16.h>
#include <math.h>

// Problem constants
#define T_LEN   4096
#define D_DIM   512
#define H_NUM   8
#define HD_DIM  64
#define W_WIN   32
#define HID_DIM 1536
#define M_ROWS  8192   // B*T

typedef __hip_bfloat16 bf16;
typedef __bf16  bf16x8 __attribute__((ext_vector_type(8)));
typedef float   f32x4  __attribute__((ext_vector_type(4)));

__device__ __forceinline__ float b2f(bf16 x) { return __bfloat162float(x); }
__device__ __forceinline__ bf16  f2b(float x){ return __float2bfloat16(x); }

__device__ __forceinline__ float rdP(const void* p, int i, bool f32) {
  return f32 ? ((const float*)p)[i] : b2f(((const bf16*)p)[i]);
}

__device__ __forceinline__ float wave_reduce_sum(float v) {
  #pragma unroll
  for (int off = 32; off; off >>= 1) v += __shfl_xor(v, off, 64);
  return v;
}

// ---------------------------------------------------------------------------
// Input-dtype detector (parallel, 64 lanes). flag=1 -> inputs are float32.
// ---------------------------------------------------------------------------
__global__ void detect_kernel(const unsigned* __restrict__ x, int* flag) {
  int lane = threadIdx.x & 63;
  int votes = 0;
  #pragma unroll
  for (int i = 0; i < 4; ++i) {
    unsigned e = (x[lane * 4 + i] >> 7) & 0xffu;  // exponent field of low half
    votes += (e >= 90u && e <= 140u) ? 1 : 0;
  }
  float v = wave_reduce_sum((float)votes);
  if (lane == 0) *flag = (v < 200.f) ? 1 : 0;
}

// ---------------------------------------------------------------------------
// LayerNorm (R2-validated).
// ---------------------------------------------------------------------------
__global__ __launch_bounds__(256) void ln_kernel(
    const void* __restrict__ in, const void* __restrict__ g, const void* __restrict__ bb,
    void* __restrict__ out, int mode,
    const void* __restrict__ freqs, const void* __restrict__ phases,
    const void* __restrict__ amp,
    const int* __restrict__ flag, int in_follows, int out_follows)
{
  bool f32  = (*flag != 0);
  bool inF  = f32 && (in_follows != 0);
  bool outF = f32 && (out_follows != 0);

  int wave = threadIdx.x >> 6;
  int lane = threadIdx.x & 63;
  int row  = blockIdx.x * 4 + wave;

  float x[8];
  if (inF) {
    const float* rp = (const float*)in + (size_t)row * D_DIM + lane * 8;
    float4 v0 = *reinterpret_cast<const float4*>(rp);
    float4 v1 = *reinterpret_cast<const float4*>(rp + 4);
    x[0]=v0.x; x[1]=v0.y; x[2]=v0.z; x[3]=v0.w;
    x[4]=v1.x; x[5]=v1.y; x[6]=v1.z; x[7]=v1.w;
  } else {
    bf16x8 v = *reinterpret_cast<const bf16x8*>(
        (const bf16*)in + (size_t)row * D_DIM + lane * 8);
    #pragma unroll
    for (int i = 0; i < 8; ++i) x[i] = (float)v[i];
  }

  float s = 0.f, s2 = 0.f;
  #pragma unroll
  for (int i = 0; i < 8; ++i) { s += x[i]; s2 += x[i]*x[i]; }
  s  = wave_reduce_sum(s);
  s2 = wave_reduce_sum(s2);
  float mu   = s * (1.f / D_DIM);
  float var  = s2 * (1.f / D_DIM) - mu * mu;
  float rstd = rsqrtf(var + 1e-5f);

  int t = row & (T_LEN - 1);
  float ampf = (mode == 1) ? rdP(amp, 0, f32) : 0.f;

  float o[8];
  #pragma unroll
  for (int i = 0; i < 8; ++i) {
    int d = lane * 8 + i;
    float val = (x[i] - mu) * rstd * rdP(g, d, f32) + rdP(bb, d, f32);
    if (mode == 1) {
      float m = sinf(fmaf((float)t, rdP(freqs, d, f32), rdP(phases, d, f32)));
      val *= (1.f + ampf * m);
    }
    o[i] = val;
  }

  if (outF) {
    float* op = (float*)out + (size_t)row * D_DIM + lane * 8;
    *reinterpret_cast<float4*>(op)     = make_float4(o[0], o[1], o[2], o[3]);
    *reinterpret_cast<float4*>(op + 4) = make_float4(o[4], o[5], o[6], o[7]);
  } else {
    bf16x8 ov;
    #pragma unroll
    for (int i = 0; i < 8; ++i) ov[i] = (__bf16)o[i];
    *reinterpret_cast<bf16x8*>((bf16*)out + (size_t)row * D_DIM + lane * 8) = ov;
  }
}

// ---------------------------------------------------------------------------
// Transpose (R x C) -> (C x R). src dtype follows flag; dst always bf16.
// ---------------------------------------------------------------------------
__global__ __launch_bounds__(256) void transpose_kernel(
    const void* __restrict__ src, bf16* __restrict__ dst, int R, int C,
    const int* __restrict__ flag)
{
  bool f32 = (*flag != 0);
  __shared__ bf16 tile[32][33];
  int tx = threadIdx.x & 31;
  int ty = threadIdx.x >> 5;
  int c0 = blockIdx.x * 32;
  int r0 = blockIdx.y * 32;
  #pragma unroll
  for (int j = 0; j < 32; j += 8)
    tile[ty + j][tx] = f2b(rdP(src, (size_t)(r0 + ty + j) * C + c0 + tx, f32));
  __syncthreads();
  #pragma unroll
  for (int j = 0; j < 32; j += 8)
    dst[(size_t)(c0 + ty + j) * R + r0 + tx] = tile[tx][ty + j];
}

// ---------------------------------------------------------------------------
// GEMM (R2-validated).
// ---------------------------------------------------------------------------
__global__ __launch_bounds__(256) void gemm_kernel(
    const bf16* __restrict__ A, const bf16* __restrict__ Bt,
    bf16* Cout, const bf16* extra, int N, int K, int mode)
{
  int lane = threadIdx.x & 63;
  int wid  = threadIdx.x >> 6;
  int quad = lane >> 4;
  int l16  = lane & 15;
  int mbase = blockIdx.y * 128 + (wid >> 1) * 64;
  int nbase = blockIdx.x * 128 + (wid & 1) * 64;

  f32x4 acc[4][4] = {};

  for (int k0 = 0; k0 < K; k0 += 32) {
    int kk = k0 + quad * 8;
    bf16x8 a[4], bb[4];
    #pragma unroll
    for (int i = 0; i < 4; ++i)
      a[i] = *reinterpret_cast<const bf16x8*>(A + (size_t)(mbase + i*16 + l16) * K + kk);
    #pragma unroll
    for (int j = 0; j < 4; ++j)
      bb[j] = *reinterpret_cast<const bf16x8*>(Bt + (size_t)(nbase + j*16 + l16) * K + kk);
    #pragma unroll
    for (int i = 0; i < 4; ++i)
      #pragma unroll
      for (int j = 0; j < 4; ++j)
        acc[i][j] = __builtin_amdgcn_mfma_f32_16x16x32_bf16(a[i], bb[j], acc[i][j], 0, 0, 0);
  }

  #pragma unroll
  for (int i = 0; i < 4; ++i) {
    #pragma unroll
    for (int j = 0; j < 4; ++j) {
      #pragma unroll
      for (int r = 0; r < 4; ++r) {
        int row = mbase + i * 16 + quad * 4 + r;
        int col = nbase + j * 16 + l16;
        size_t idx = (size_t)row * N + col;
        float c = acc[i][j][r];
        if (mode == 1) {
          c += b2f(extra[idx]);
        } else if (mode == 2) {
          float gg = b2f(extra[idx]);
          c *= gg / (1.f + expf(-gg));
        }
        Cout[idx] = f2b(c);
      }
    }
  }
}

// ---------------------------------------------------------------------------
// MFMA sliding-window sigmoid attention.
// One wave per (16-token tile, head). Rel-token axis j = 0..46 maps to
// token rowbase-32+j; query i valid keys: i <= j <= i+31 and t0-32+j >= 0.
// S = Q(16x64) @ K_rel(48x64)^T  (6 mfma), tau = sigmoid(S/8) masked,
// P -> LDS (C-layout to A-layout), V staged transposed in LDS,
// M = P(16x64pad) @ V(64x64) (8 mfma). msg overwrites q (own rows only).
//
// V^T layout: vt_addr(d,t) = d*144 + 2t. Row span = 128 B <= stride 144 B
// (R3 bug: stride 112 B made rows overlap -> zero-fill clobbered tokens 0..7
// of the next dim row). 144 = 9*16 keeps b128 reads 16-aligned; lane stride
// 36 dwords -> 2-way bank aliasing (free, m136).
// ---------------------------------------------------------------------------
#define VT_BYTES 9216   // 64 rows * 144 B
#define PL_BYTES 2304   // P: 16 rows x 72 bf16
__device__ __forceinline__ int vt_addr(int d, int t) {
  return d * 144 + t * 2;
}

__global__ __launch_bounds__(256) void attn_mfma_kernel(
    const bf16* q, const bf16* __restrict__ kv, bf16* msg)
{
  __shared__ alignas(16) char lds_raw[4 * (VT_BYTES + PL_BYTES)];
  int lane = threadIdx.x & 63;
  int widx = threadIdx.x >> 6;
  int u    = blockIdx.x * 4 + widx;
  int tile = u >> 3, head = u & 7;
  int rowbase = tile * 16;            // global query row base
  int t0   = rowbase & (T_LEN - 1);   // position within its sequence
  int l16  = lane & 15, quad = lane >> 4;

  char* wbase = lds_raw + widx * (VT_BYTES + PL_BYTES);
  char* Vl = wbase;                   // V^T
  bf16* Pl = (bf16*)(wbase + VT_BYTES);

  // ---- Stage V transposed into LDS: tokens t=0..47 (clamped rows), dims 0..63.
  {
    #pragma unroll
    for (int it = 0; it < 6; ++it) {
      int chunk = it * 64 + lane;
      int t  = chunk >> 3;            // 0..47
      int dc = chunk & 7;             // dim chunk (8 dims)
      int row = rowbase - 32 + t;
      if (row < 0) row = 0;           // garbage ok: masked by tau=0
      bf16x8 v = *reinterpret_cast<const bf16x8*>(
          kv + (size_t)row * 1024 + head * 128 + 64 + dc * 8);
      #pragma unroll
      for (int jj = 0; jj < 8; ++jj)
        *(bf16*)(Vl + vt_addr(dc * 8 + jj, t)) = (bf16)(__bf16)v[jj];
    }
    // zero-fill tokens 48..63 (K-dim padding): lane=d writes 16 bf16 = 2x16B
    bf16x8 z = {};
    *reinterpret_cast<bf16x8*>(Vl + vt_addr(lane, 48)) = z;
    *reinterpret_cast<bf16x8*>(Vl + vt_addr(lane, 56)) = z;
  }

  // ---- Q a-frags (dims of this head, 2 K-chunks)
  bf16x8 aq0, aq1;
  {
    const bf16* qrow = q + (size_t)(rowbase + l16) * D_DIM + head * HD_DIM + quad * 8;
    aq0 = *reinterpret_cast<const bf16x8*>(qrow);
    aq1 = *reinterpret_cast<const bf16x8*>(qrow + 32);
  }

  // ---- S = Q @ K^T over 3 j-tiles
  f32x4 sacc[3] = {};
  #pragma unroll
  for (int jt = 0; jt < 3; ++jt) {
    int tok = rowbase - 32 + jt * 16 + l16;
    if (tok < 0) tok = 0;             // garbage ok: masked
    const bf16* krow = kv + (size_t)tok * 1024 + head * 128 + quad * 8;
    bf16x8 b0 = *reinterpret_cast<const bf16x8*>(krow);
    bf16x8 b1 = *reinterpret_cast<const bf16x8*>(krow + 32);
    sacc[jt] = __builtin_amdgcn_mfma_f32_16x16x32_bf16(aq0, b0, sacc[jt], 0, 0, 0);
    sacc[jt] = __builtin_amdgcn_mfma_f32_16x16x32_bf16(aq1, b1, sacc[jt], 0, 0, 0);
  }

  // ---- mask + sigmoid, write P to LDS (C-layout: row i=quad*4+r, col j=jt*16+l16)
  #pragma unroll
  for (int jt = 0; jt < 3; ++jt) {
    int j = jt * 16 + l16;
    #pragma unroll
    for (int r = 0; r < 4; ++r) {
      int i = quad * 4 + r;
      bool valid = (j >= i) && (j <= i + 31) && (t0 - 32 + j >= 0);
      float tau = valid ? 1.f / (1.f + expf(-sacc[jt][r] * 0.125f)) : 0.f;
      Pl[i * 72 + j] = f2b(tau);
    }
  }
  {  // zero-pad P cols 48..63
    #pragma unroll
    for (int r = 0; r < 4; ++r) Pl[(quad * 4 + r) * 72 + 48 + l16] = f2b(0.f);
  }

  __syncthreads();  // uniform; orders LDS writes->reads

  // ---- P a-frags from LDS (A-layout: m=l16, k=quad*8+idx)
  bf16x8 ap0 = *reinterpret_cast<const bf16x8*>((char*)Pl + l16 * 144 + quad * 16);
  bf16x8 ap1 = *reinterpret_cast<const bf16x8*>((char*)Pl + l16 * 144 + 64 + quad * 16);

  // ---- M = P @ V over 4 dim-tiles
  f32x4 macc[4] = {};
  #pragma unroll
  for (int nt = 0; nt < 4; ++nt) {
    int d = nt * 16 + l16;
    bf16x8 bv0 = *reinterpret_cast<const bf16x8*>(Vl + vt_addr(d, quad * 8));
    bf16x8 bv1 = *reinterpret_cast<const bf16x8*>(Vl + vt_addr(d, 32 + quad * 8));
    macc[nt] = __builtin_amdgcn_mfma_f32_16x16x32_bf16(ap0, bv0, macc[nt], 0, 0, 0);
    macc[nt] = __builtin_amdgcn_mfma_f32_16x16x32_bf16(ap1, bv1, macc[nt], 0, 0, 0);
  }

  // ---- store msg (overwrites q; this wave's own rows/cols only)
  #pragma unroll
  for (int nt = 0; nt < 4; ++nt)
    #pragma unroll
    for (int r = 0; r < 4; ++r)
      msg[(size_t)(rowbase + quad * 4 + r) * D_DIM + head * HD_DIM + nt * 16 + l16] =
          f2b(macc[nt][r]);
}

// ---------------------------------------------------------------------------
extern "C" void kernel_launch(void* const* d_in, const int* in_sizes, int n_in,
                              void* d_out, int out_size, void* d_ws, size_t ws_size,
                              hipStream_t stream)
{
  const void* x      = d_in[0];
  const void* pre_g  = d_in[1];
  const void* pre_b  = d_in[2];
  const void* wq     = d_in[3];
  const void* wkv    = d_in[4];
  const void* wo     = d_in[5];
  const void* attn_g = d_in[6];
  const void* attn_b = d_in[7];
  const void* freqs  = d_in[8];
  const void* phases = d_in[9];
  const void* amp    = d_in[10];
  const void* w_gate = d_in[11];
  const void* w_val  = d_in[12];
  const void* w_proj = d_in[13];
  const void* ffn_g  = d_in[14];
  const void* ffn_b  = d_in[15];

  char* ws = (char*)d_ws;
  int*  flag = (int*)(ws + 0);
  bf16* Btq  = (bf16*)(ws + 512);
  bf16* Btkv = (bf16*)(ws + 524800);
  bf16* Bto  = (bf16*)(ws + 1573376);
  bf16* Btg  = (bf16*)(ws + 2097664);
  bf16* Btv  = (bf16*)(ws + 3670528);
  bf16* Btp  = (bf16*)(ws + 5243392);
  bf16* h    = (bf16*)(ws + 6816256);   // 8192 x  512
  bf16* qb   = (bf16*)(ws + 15204864);  // 8192 x  512 (q -> msg in place)
  bf16* kvb  = (bf16*)(ws + 23593472);  // 8192 x 1024
  bf16* gb   = qb;                      // 8192 x 1536 (FFN reuses q+kv region)

  detect_kernel<<<1, 64, 0, stream>>>((const unsigned*)x, flag);

  transpose_kernel<<<dim3(16, 16), 256, 0, stream>>>(wq,     Btq,  512,  512, flag);
  transpose_kernel<<<dim3(32, 16), 256, 0, stream>>>(wkv,    Btkv, 512, 1024, flag);
  transpose_kernel<<<dim3(16, 16), 256, 0, stream>>>(wo,     Bto,  512,  512, flag);
  transpose_kernel<<<dim3(48, 16), 256, 0, stream>>>(w_gate, Btg,  512, 1536, flag);
  transpose_kernel<<<dim3(48, 16), 256, 0, stream>>>(w_val,  Btv,  512, 1536, flag);
  transpose_kernel<<<dim3(16, 48), 256, 0, stream>>>(w_proj, Btp, 1536,  512, flag);

  ln_kernel<<<2048, 256, 0, stream>>>(x, pre_g, pre_b, h, 0,
                                      nullptr, nullptr, nullptr, flag, 1, 0);

  gemm_kernel<<<dim3(4, 64),  256, 0, stream>>>(h, Btq,  qb,  nullptr,  512, 512, 0);
  gemm_kernel<<<dim3(8, 64),  256, 0, stream>>>(h, Btkv, kvb, nullptr, 1024, 512, 0);

  attn_mfma_kernel<<<1024, 256, 0, stream>>>(qb, kvb, qb);

  gemm_kernel<<<dim3(4, 64),  256, 0, stream>>>(qb, Bto, h, h, 512, 512, 1);

  ln_kernel<<<2048, 256, 0, stream>>>(h, attn_g, attn_b, h, 1,
                                      freqs, phases, amp, flag, 0, 0);

  gemm_kernel<<<dim3(12, 64), 256, 0, stream>>>(h, Btg, gb, nullptr, 1536, 512, 0);
  gemm_kernel<<<dim3(12, 64), 256, 0, stream>>>(h, Btv, gb, gb,      1536, 512, 2);

  gemm_kernel<<<dim3(4, 64),  256, 0, stream>>>(gb, Btp, h, h, 512, 1536, 1);

  ln_kernel<<<2048, 256, 0, stream>>>(h, ffn_g, ffn_b, d_out, 0,
                                      nullptr, nullptr, nullptr, flag, 0, 1);
}

// Round 5
// 381.909 us; speedup vs baseline: 1.5886x; 1.2284x over previous
//
#include <hip/hip_runtime.h>
#include <hip/hip_bf16.h>
#include <math.h>

// Problem constants
#define T_LEN   4096
#define D_DIM   512
#define H_NUM   8
#define HD_DIM  64
#define W_WIN   32
#define HID_DIM 1536
#define M_ROWS  8192   // B*T
#define QKV_LD  1536   // fused q|kv row stride

typedef __hip_bfloat16 bf16;
typedef __bf16  bf16x8 __attribute__((ext_vector_type(8)));
typedef float   f32x4  __attribute__((ext_vector_type(4)));

__device__ __forceinline__ float b2f(bf16 x) { return __bfloat162float(x); }
__device__ __forceinline__ bf16  f2b(float x){ return __float2bfloat16(x); }

__device__ __forceinline__ float rdP(const void* p, int i, bool f32) {
  return f32 ? ((const float*)p)[i] : b2f(((const bf16*)p)[i]);
}

__device__ __forceinline__ float wave_reduce_sum(float v) {
  #pragma unroll
  for (int off = 32; off; off >>= 1) v += __shfl_xor(v, off, 64);
  return v;
}

// Async global->LDS, 16B per lane. lds must be wave-uniform; HW writes
// lds + lane*16. gptr is per-lane. [m97 pattern]
__device__ __forceinline__ void gload_lds16(const bf16* g, bf16* l) {
  __builtin_amdgcn_global_load_lds(
      (const __attribute__((address_space(1))) unsigned int*)g,
      (__attribute__((address_space(3))) unsigned int*)l, 16, 0, 0);
}

// ---------------------------------------------------------------------------
// Input-dtype detector. flag=1 -> inputs are float32.
// ---------------------------------------------------------------------------
__global__ void detect_kernel(const unsigned* __restrict__ x, int* flag) {
  int lane = threadIdx.x & 63;
  int votes = 0;
  #pragma unroll
  for (int i = 0; i < 4; ++i) {
    unsigned e = (x[lane * 4 + i] >> 7) & 0xffu;
    votes += (e >= 90u && e <= 140u) ? 1 : 0;
  }
  float v = wave_reduce_sum((float)votes);
  if (lane == 0) *flag = (v < 200.f) ? 1 : 0;
}

// ---------------------------------------------------------------------------
// LayerNorm (R2-validated).
// ---------------------------------------------------------------------------
__global__ __launch_bounds__(256) void ln_kernel(
    const void* __restrict__ in, const void* __restrict__ g, const void* __restrict__ bb,
    void* __restrict__ out, int mode,
    const void* __restrict__ freqs, const void* __restrict__ phases,
    const void* __restrict__ amp,
    const int* __restrict__ flag, int in_follows, int out_follows)
{
  bool f32  = (*flag != 0);
  bool inF  = f32 && (in_follows != 0);
  bool outF = f32 && (out_follows != 0);

  int wave = threadIdx.x >> 6;
  int lane = threadIdx.x & 63;
  int row  = blockIdx.x * 4 + wave;

  float x[8];
  if (inF) {
    const float* rp = (const float*)in + (size_t)row * D_DIM + lane * 8;
    float4 v0 = *reinterpret_cast<const float4*>(rp);
    float4 v1 = *reinterpret_cast<const float4*>(rp + 4);
    x[0]=v0.x; x[1]=v0.y; x[2]=v0.z; x[3]=v0.w;
    x[4]=v1.x; x[5]=v1.y; x[6]=v1.z; x[7]=v1.w;
  } else {
    bf16x8 v = *reinterpret_cast<const bf16x8*>(
        (const bf16*)in + (size_t)row * D_DIM + lane * 8);
    #pragma unroll
    for (int i = 0; i < 8; ++i) x[i] = (float)v[i];
  }

  float s = 0.f, s2 = 0.f;
  #pragma unroll
  for (int i = 0; i < 8; ++i) { s += x[i]; s2 += x[i]*x[i]; }
  s  = wave_reduce_sum(s);
  s2 = wave_reduce_sum(s2);
  float mu   = s * (1.f / D_DIM);
  float var  = s2 * (1.f / D_DIM) - mu * mu;
  float rstd = rsqrtf(var + 1e-5f);

  int t = row & (T_LEN - 1);
  float ampf = (mode == 1) ? rdP(amp, 0, f32) : 0.f;

  float o[8];
  #pragma unroll
  for (int i = 0; i < 8; ++i) {
    int d = lane * 8 + i;
    float val = (x[i] - mu) * rstd * rdP(g, d, f32) + rdP(bb, d, f32);
    if (mode == 1) {
      float m = sinf(fmaf((float)t, rdP(freqs, d, f32), rdP(phases, d, f32)));
      val *= (1.f + ampf * m);
    }
    o[i] = val;
  }

  if (outF) {
    float* op = (float*)out + (size_t)row * D_DIM + lane * 8;
    *reinterpret_cast<float4*>(op)     = make_float4(o[0], o[1], o[2], o[3]);
    *reinterpret_cast<float4*>(op + 4) = make_float4(o[4], o[5], o[6], o[7]);
  } else {
    bf16x8 ov;
    #pragma unroll
    for (int i = 0; i < 8; ++i) ov[i] = (__bf16)o[i];
    *reinterpret_cast<bf16x8*>((bf16*)out + (size_t)row * D_DIM + lane * 8) = ov;
  }
}

// ---------------------------------------------------------------------------
// Transpose (R x C) -> (C x R). src dtype follows flag; dst always bf16.
// ---------------------------------------------------------------------------
__global__ __launch_bounds__(256) void transpose_kernel(
    const void* __restrict__ src, bf16* __restrict__ dst, int R, int C,
    const int* __restrict__ flag)
{
  bool f32 = (*flag != 0);
  __shared__ bf16 tile[32][33];
  int tx = threadIdx.x & 31;
  int ty = threadIdx.x >> 5;
  int c0 = blockIdx.x * 32;
  int r0 = blockIdx.y * 32;
  #pragma unroll
  for (int j = 0; j < 32; j += 8)
    tile[ty + j][tx] = f2b(rdP(src, (size_t)(r0 + ty + j) * C + c0 + tx, f32));
  __syncthreads();
  #pragma unroll
  for (int j = 0; j < 32; j += 8)
    dst[(size_t)(c0 + ty + j) * R + r0 + tx] = tile[tx][ty + j];
}

// ---------------------------------------------------------------------------
// LDS-staged GEMM (m97 structure): C[M x N] = A[M x K] @ Bt^T, Bt is [N x K].
// 128x128 block tile, BK=64, 4 waves (each 64x64 via 4x4 mfma 16x16x32).
// Staging: global_load_lds width=16, XOR-swizzled 16B chunks:
//   LDS[row][c] = global[row][c ^ (row&7)]   (row stride 64 elem = 128 B)
// so ds_read_b128 fragment reads spread 16 lanes over 8 chunk slots
// (2-way bank aliasing = free, m136), while staging keeps the required
// wave-uniform-base + lane*16 contract (lane l -> row l>>3, chunk l&7,
// global chunk (l&7)^(l>>3) since row%8 == l>>3).
// lda = A row stride (elements). mode 0: C. 1: C+extra. 2: silu(extra)*C.
// ---------------------------------------------------------------------------
#define BK 64
__global__ __launch_bounds__(256) void gemm_kernel(
    const bf16* __restrict__ A, const bf16* __restrict__ Bt,
    bf16* Cout, const bf16* extra, int N, int K, int lda, int mode)
{
  __shared__ alignas(16) bf16 As[128 * BK];
  __shared__ alignas(16) bf16 Bs[128 * BK];

  int lane = threadIdx.x & 63;
  int wid  = threadIdx.x >> 6;
  int quad = lane >> 4;
  int l16  = lane & 15;
  int mbase = blockIdx.y * 128;
  int nbase = blockIdx.x * 128;
  int wm = (wid >> 1) * 64;
  int wn = (wid & 1) * 64;

  // Staging source pointers: lane l covers row (wid*32 + it*8 + (l>>3)),
  // global chunk (l&7)^(l>>3), 16 B each.
  int srow   = wid * 32 + (lane >> 3);
  int schunk = (lane & 7) ^ (lane >> 3);
  const bf16* Ag = A  + (size_t)(mbase + srow) * lda + schunk * 8;
  const bf16* Bg = Bt + (size_t)(nbase + srow) * K   + schunk * 8;

  f32x4 acc[4][4] = {};

  for (int k0 = 0; k0 < K; k0 += BK) {
    __syncthreads();   // previous iteration's ds_reads done before overwrite
    #pragma unroll
    for (int it = 0; it < 4; ++it) {
      gload_lds16(Ag + (size_t)(it * 8) * lda + k0, &As[(wid * 32 + it * 8) * BK]);
      gload_lds16(Bg + (size_t)(it * 8) * K   + k0, &Bs[(wid * 32 + it * 8) * BK]);
    }
    __syncthreads();   // staging visible (compiler drains vmcnt before barrier)

    #pragma unroll
    for (int ko = 0; ko < 2; ++ko) {
      bf16x8 a[4], b[4];
      #pragma unroll
      for (int i = 0; i < 4; ++i) {
        int row = wm + i * 16 + l16;
        int c = (ko * 4 + quad) ^ (l16 & 7);
        a[i] = *reinterpret_cast<const bf16x8*>(&As[row * BK + c * 8]);
      }
      #pragma unroll
      for (int j = 0; j < 4; ++j) {
        int row = wn + j * 16 + l16;
        int c = (ko * 4 + quad) ^ (l16 & 7);
        b[j] = *reinterpret_cast<const bf16x8*>(&Bs[row * BK + c * 8]);
      }
      #pragma unroll
      for (int i = 0; i < 4; ++i)
        #pragma unroll
        for (int j = 0; j < 4; ++j)
          acc[i][j] = __builtin_amdgcn_mfma_f32_16x16x32_bf16(a[i], b[j], acc[i][j], 0, 0, 0);
    }
  }

  #pragma unroll
  for (int i = 0; i < 4; ++i) {
    #pragma unroll
    for (int j = 0; j < 4; ++j) {
      #pragma unroll
      for (int r = 0; r < 4; ++r) {
        int row = mbase + wm + i * 16 + quad * 4 + r;
        int col = nbase + wn + j * 16 + l16;
        size_t idx = (size_t)row * N + col;
        float c = acc[i][j][r];
        if (mode == 1) {
          c += b2f(extra[idx]);
        } else if (mode == 2) {
          float gg = b2f(extra[idx]);
          c *= gg / (1.f + expf(-gg));
        }
        Cout[idx] = f2b(c);
      }
    }
  }
}

// ---------------------------------------------------------------------------
// MFMA sliding-window sigmoid attention over the fused qkv buffer
// (row stride QKV_LD; q at col 0, k at 512+head*128, v at 512+head*128+64).
// msg overwrites the q slot (own rows/cols only; no cross-wave overlap).
// ---------------------------------------------------------------------------
#define VT_BYTES 9216   // 64 rows * 144 B  (stride 144 B >= 128 B span; R3 fix)
#define PL_BYTES 2304   // P: 16 rows x 72 bf16
__device__ __forceinline__ int vt_addr(int d, int t) {
  return d * 144 + t * 2;
}

__global__ __launch_bounds__(256) void attn_mfma_kernel(bf16* qkv)
{
  __shared__ alignas(16) char lds_raw[4 * (VT_BYTES + PL_BYTES)];
  int lane = threadIdx.x & 63;
  int widx = threadIdx.x >> 6;
  int u    = blockIdx.x * 4 + widx;
  int tile = u >> 3, head = u & 7;
  int rowbase = tile * 16;
  int t0   = rowbase & (T_LEN - 1);
  int l16  = lane & 15, quad = lane >> 4;

  char* wbase = lds_raw + widx * (VT_BYTES + PL_BYTES);
  char* Vl = wbase;
  bf16* Pl = (bf16*)(wbase + VT_BYTES);

  // ---- Stage V^T into LDS: tokens t=0..47 (clamped), dims 0..63.
  {
    #pragma unroll
    for (int it = 0; it < 6; ++it) {
      int chunk = it * 64 + lane;
      int t  = chunk >> 3;
      int dc = chunk & 7;
      int row = rowbase - 32 + t;
      if (row < 0) row = 0;           // garbage ok: masked by tau=0
      bf16x8 v = *reinterpret_cast<const bf16x8*>(
          qkv + (size_t)row * QKV_LD + 512 + head * 128 + 64 + dc * 8);
      #pragma unroll
      for (int jj = 0; jj < 8; ++jj)
        *(bf16*)(Vl + vt_addr(dc * 8 + jj, t)) = (bf16)(__bf16)v[jj];
    }
    bf16x8 z = {};
    *reinterpret_cast<bf16x8*>(Vl + vt_addr(lane, 48)) = z;
    *reinterpret_cast<bf16x8*>(Vl + vt_addr(lane, 56)) = z;
  }

  // ---- Q a-frags
  bf16x8 aq0, aq1;
  {
    const bf16* qrow = qkv + (size_t)(rowbase + l16) * QKV_LD + head * HD_DIM + quad * 8;
    aq0 = *reinterpret_cast<const bf16x8*>(qrow);
    aq1 = *reinterpret_cast<const bf16x8*>(qrow + 32);
  }

  // ---- S = Q @ K^T over 3 j-tiles
  f32x4 sacc[3] = {};
  #pragma unroll
  for (int jt = 0; jt < 3; ++jt) {
    int tok = rowbase - 32 + jt * 16 + l16;
    if (tok < 0) tok = 0;             // garbage ok: masked
    const bf16* krow = qkv + (size_t)tok * QKV_LD + 512 + head * 128 + quad * 8;
    bf16x8 b0 = *reinterpret_cast<const bf16x8*>(krow);
    bf16x8 b1 = *reinterpret_cast<const bf16x8*>(krow + 32);
    sacc[jt] = __builtin_amdgcn_mfma_f32_16x16x32_bf16(aq0, b0, sacc[jt], 0, 0, 0);
    sacc[jt] = __builtin_amdgcn_mfma_f32_16x16x32_bf16(aq1, b1, sacc[jt], 0, 0, 0);
  }

  // ---- mask + sigmoid -> P in LDS (C-layout write)
  #pragma unroll
  for (int jt = 0; jt < 3; ++jt) {
    int j = jt * 16 + l16;
    #pragma unroll
    for (int r = 0; r < 4; ++r) {
      int i = quad * 4 + r;
      bool valid = (j >= i) && (j <= i + 31) && (t0 - 32 + j >= 0);
      float tau = valid ? 1.f / (1.f + expf(-sacc[jt][r] * 0.125f)) : 0.f;
      Pl[i * 72 + j] = f2b(tau);
    }
  }
  {
    #pragma unroll
    for (int r = 0; r < 4; ++r) Pl[(quad * 4 + r) * 72 + 48 + l16] = f2b(0.f);
  }

  __syncthreads();

  // ---- P a-frags (A-layout read)
  bf16x8 ap0 = *reinterpret_cast<const bf16x8*>((char*)Pl + l16 * 144 + quad * 16);
  bf16x8 ap1 = *reinterpret_cast<const bf16x8*>((char*)Pl + l16 * 144 + 64 + quad * 16);

  // ---- M = P @ V over 4 dim-tiles
  f32x4 macc[4] = {};
  #pragma unroll
  for (int nt = 0; nt < 4; ++nt) {
    int d = nt * 16 + l16;
    bf16x8 bv0 = *reinterpret_cast<const bf16x8*>(Vl + vt_addr(d, quad * 8));
    bf16x8 bv1 = *reinterpret_cast<const bf16x8*>(Vl + vt_addr(d, 32 + quad * 8));
    macc[nt] = __builtin_amdgcn_mfma_f32_16x16x32_bf16(ap0, bv0, macc[nt], 0, 0, 0);
    macc[nt] = __builtin_amdgcn_mfma_f32_16x16x32_bf16(ap1, bv1, macc[nt], 0, 0, 0);
  }

  // ---- store msg into the q slot (own rows/cols only)
  #pragma unroll
  for (int nt = 0; nt < 4; ++nt)
    #pragma unroll
    for (int r = 0; r < 4; ++r)
      qkv[(size_t)(rowbase + quad * 4 + r) * QKV_LD + head * HD_DIM + nt * 16 + l16] =
          f2b(macc[nt][r]);
}

// ---------------------------------------------------------------------------
extern "C" void kernel_launch(void* const* d_in, const int* in_sizes, int n_in,
                              void* d_out, int out_size, void* d_ws, size_t ws_size,
                              hipStream_t stream)
{
  const void* x      = d_in[0];
  const void* pre_g  = d_in[1];
  const void* pre_b  = d_in[2];
  const void* wq     = d_in[3];
  const void* wkv    = d_in[4];
  const void* wo     = d_in[5];
  const void* attn_g = d_in[6];
  const void* attn_b = d_in[7];
  const void* freqs  = d_in[8];
  const void* phases = d_in[9];
  const void* amp    = d_in[10];
  const void* w_gate = d_in[11];
  const void* w_val  = d_in[12];
  const void* w_proj = d_in[13];
  const void* ffn_g  = d_in[14];
  const void* ffn_b  = d_in[15];

  char* ws = (char*)d_ws;
  int*  flag  = (int*)(ws + 0);
  bf16* Btqkv = (bf16*)(ws + 512);       // 1536 x 512 (wq rows 0..511, wkv rows 512..1535)
  bf16* Bto   = (bf16*)(ws + 1573376);   //  512 x 512
  bf16* Btg   = (bf16*)(ws + 2097664);   // 1536 x 512
  bf16* Btv   = (bf16*)(ws + 3670528);   // 1536 x 512
  bf16* Btp   = (bf16*)(ws + 5243392);   //  512 x 1536
  bf16* h     = (bf16*)(ws + 6816256);   // 8192 x 512   (h -> s1 -> y -> u)
  bf16* qkvb  = (bf16*)(ws + 15204864);  // 8192 x 1536  (q|kv; msg in-place; then gb)
  bf16* gb    = qkvb;                    // FFN gate/act reuses qkv region

  detect_kernel<<<1, 64, 0, stream>>>((const unsigned*)x, flag);

  // weight transposes -> [N x K] bf16
  transpose_kernel<<<dim3(16, 16), 256, 0, stream>>>(wq,     Btqkv,            512,  512, flag);
  transpose_kernel<<<dim3(32, 16), 256, 0, stream>>>(wkv,    Btqkv + 512*512,  512, 1024, flag);
  transpose_kernel<<<dim3(16, 16), 256, 0, stream>>>(wo,     Bto,              512,  512, flag);
  transpose_kernel<<<dim3(48, 16), 256, 0, stream>>>(w_gate, Btg,              512, 1536, flag);
  transpose_kernel<<<dim3(48, 16), 256, 0, stream>>>(w_val,  Btv,              512, 1536, flag);
  transpose_kernel<<<dim3(16, 48), 256, 0, stream>>>(w_proj, Btp,             1536,  512, flag);

  // h = LN(x)
  ln_kernel<<<2048, 256, 0, stream>>>(x, pre_g, pre_b, h, 0,
                                      nullptr, nullptr, nullptr, flag, 1, 0);

  // qkv = h @ [wq|wkv]  (fused, N=1536)
  gemm_kernel<<<dim3(12, 64), 256, 0, stream>>>(h, Btqkv, qkvb, nullptr, 1536, 512, 512, 0);

  // msg = window-attention (in-place over q slot)
  attn_mfma_kernel<<<1024, 256, 0, stream>>>(qkvb);

  // s1 = h + msg @ wo
  gemm_kernel<<<dim3(4, 64),  256, 0, stream>>>(qkvb, Bto, h, h, 512, 512, QKV_LD, 1);

  // y = LN(s1) * (1 + amp*sin(...))
  ln_kernel<<<2048, 256, 0, stream>>>(h, attn_g, attn_b, h, 1,
                                      freqs, phases, amp, flag, 0, 0);

  // g = y @ w_gate ; act = silu(g) * (y @ w_val)
  gemm_kernel<<<dim3(12, 64), 256, 0, stream>>>(h, Btg, gb, nullptr, 1536, 512, 512, 0);
  gemm_kernel<<<dim3(12, 64), 256, 0, stream>>>(h, Btv, gb, gb,      1536, 512, 512, 2);

  // u = y + act @ w_proj
  gemm_kernel<<<dim3(4, 64),  256, 0, stream>>>(gb, Btp, h, h, 512, 1536, QKV_LD, 1);

  // out = LN(u)
  ln_kernel<<<2048, 256, 0, stream>>>(h, ffn_g, ffn_b, d_out, 0,
                                      nullptr, nullptr, nullptr, flag, 0, 1);
}

// Round 6
// 325.135 us; speedup vs baseline: 1.8660x; 1.1746x over previous
//
#include <hip/hip_runtime.h>
#include <hip/hip_bf16.h>
#include <math.h>

// Problem constants
#define T_LEN   4096
#define D_DIM   512
#define H_NUM   8
#define HD_DIM  64
#define W_WIN   32
#define HID_DIM 1536
#define M_ROWS  8192   // B*T
#define QKV_LD  1536   // fused q|kv row stride

typedef __hip_bfloat16 bf16;
typedef __bf16  bf16x8 __attribute__((ext_vector_type(8)));
typedef float   f32x4  __attribute__((ext_vector_type(4)));

__device__ __forceinline__ float b2f(bf16 x) { return __bfloat162float(x); }
__device__ __forceinline__ bf16  f2b(float x){ return __float2bfloat16(x); }

__device__ __forceinline__ float rdP(const void* p, int i, bool f32) {
  return f32 ? ((const float*)p)[i] : b2f(((const bf16*)p)[i]);
}

__device__ __forceinline__ float wave_reduce_sum(float v) {
  #pragma unroll
  for (int off = 32; off; off >>= 1) v += __shfl_xor(v, off, 64);
  return v;
}

// Async global->LDS, 16B per lane; HW writes lds + lane*16 (wave-uniform base).
__device__ __forceinline__ void gload_lds16(const bf16* g, bf16* l) {
  __builtin_amdgcn_global_load_lds(
      (const __attribute__((address_space(1))) unsigned int*)g,
      (__attribute__((address_space(3))) unsigned int*)l, 16, 0, 0);
}

// ---------------------------------------------------------------------------
// Input-dtype detector. flag=1 -> inputs are float32.
// ---------------------------------------------------------------------------
__global__ void detect_kernel(const unsigned* __restrict__ x, int* flag) {
  int lane = threadIdx.x & 63;
  int votes = 0;
  #pragma unroll
  for (int i = 0; i < 4; ++i) {
    unsigned e = (x[lane * 4 + i] >> 7) & 0xffu;
    votes += (e >= 90u && e <= 140u) ? 1 : 0;
  }
  float v = wave_reduce_sum((float)votes);
  if (lane == 0) *flag = (v < 200.f) ? 1 : 0;
}

// ---------------------------------------------------------------------------
// LayerNorm (R2-validated).
// ---------------------------------------------------------------------------
__global__ __launch_bounds__(256) void ln_kernel(
    const void* __restrict__ in, const void* __restrict__ g, const void* __restrict__ bb,
    void* __restrict__ out, int mode,
    const void* __restrict__ freqs, const void* __restrict__ phases,
    const void* __restrict__ amp,
    const int* __restrict__ flag, int in_follows, int out_follows)
{
  bool f32  = (*flag != 0);
  bool inF  = f32 && (in_follows != 0);
  bool outF = f32 && (out_follows != 0);

  int wave = threadIdx.x >> 6;
  int lane = threadIdx.x & 63;
  int row  = blockIdx.x * 4 + wave;

  float x[8];
  if (inF) {
    const float* rp = (const float*)in + (size_t)row * D_DIM + lane * 8;
    float4 v0 = *reinterpret_cast<const float4*>(rp);
    float4 v1 = *reinterpret_cast<const float4*>(rp + 4);
    x[0]=v0.x; x[1]=v0.y; x[2]=v0.z; x[3]=v0.w;
    x[4]=v1.x; x[5]=v1.y; x[6]=v1.z; x[7]=v1.w;
  } else {
    bf16x8 v = *reinterpret_cast<const bf16x8*>(
        (const bf16*)in + (size_t)row * D_DIM + lane * 8);
    #pragma unroll
    for (int i = 0; i < 8; ++i) x[i] = (float)v[i];
  }

  float s = 0.f, s2 = 0.f;
  #pragma unroll
  for (int i = 0; i < 8; ++i) { s += x[i]; s2 += x[i]*x[i]; }
  s  = wave_reduce_sum(s);
  s2 = wave_reduce_sum(s2);
  float mu   = s * (1.f / D_DIM);
  float var  = s2 * (1.f / D_DIM) - mu * mu;
  float rstd = rsqrtf(var + 1e-5f);

  int t = row & (T_LEN - 1);
  float ampf = (mode == 1) ? rdP(amp, 0, f32) : 0.f;

  float o[8];
  #pragma unroll
  for (int i = 0; i < 8; ++i) {
    int d = lane * 8 + i;
    float val = (x[i] - mu) * rstd * rdP(g, d, f32) + rdP(bb, d, f32);
    if (mode == 1) {
      float m = sinf(fmaf((float)t, rdP(freqs, d, f32), rdP(phases, d, f32)));
      val *= (1.f + ampf * m);
    }
    o[i] = val;
  }

  if (outF) {
    float* op = (float*)out + (size_t)row * D_DIM + lane * 8;
    *reinterpret_cast<float4*>(op)     = make_float4(o[0], o[1], o[2], o[3]);
    *reinterpret_cast<float4*>(op + 4) = make_float4(o[4], o[5], o[6], o[7]);
  } else {
    bf16x8 ov;
    #pragma unroll
    for (int i = 0; i < 8; ++i) ov[i] = (__bf16)o[i];
    *reinterpret_cast<bf16x8*>((bf16*)out + (size_t)row * D_DIM + lane * 8) = ov;
  }
}

// ---------------------------------------------------------------------------
// Fused weight transposes: all 6 matrices in one dispatch. Each 32x32 tile
// block looks up its matrix by block-id range. dst always bf16 [C x R].
// ---------------------------------------------------------------------------
struct TransDesc { const void* src; bf16* dst; int R, C, start, tiles_x; };

__global__ __launch_bounds__(256) void transpose_all_kernel(
    const void* s0, const void* s1, const void* s2, const void* s3,
    const void* s4, const void* s5,
    bf16* d0, bf16* d1, bf16* d2, bf16* d3, bf16* d4, bf16* d5,
    const int* __restrict__ flag)
{
  // ranges: wq[0,256) wkv[256,768) wo[768,1024) wg[1024,1792) wv[1792,2560) wp[2560,3328)
  bool f32 = (*flag != 0);
  int bid = blockIdx.x;
  const void* src; bf16* dst; int R, C, lid, tiles_x;
  if      (bid < 256)  { src=s0; dst=d0; R=512;  C=512;  lid=bid;      tiles_x=16; }
  else if (bid < 768)  { src=s1; dst=d1; R=512;  C=1024; lid=bid-256;  tiles_x=32; }
  else if (bid < 1024) { src=s2; dst=d2; R=512;  C=512;  lid=bid-768;  tiles_x=16; }
  else if (bid < 1792) { src=s3; dst=d3; R=512;  C=1536; lid=bid-1024; tiles_x=48; }
  else if (bid < 2560) { src=s4; dst=d4; R=512;  C=1536; lid=bid-1792; tiles_x=48; }
  else                 { src=s5; dst=d5; R=1536; C=512;  lid=bid-2560; tiles_x=16; }

  __shared__ bf16 tile[32][33];
  int tx = threadIdx.x & 31;
  int ty = threadIdx.x >> 5;
  int c0 = (lid % tiles_x) * 32;
  int r0 = (lid / tiles_x) * 32;
  #pragma unroll
  for (int j = 0; j < 32; j += 8)
    tile[ty + j][tx] = f2b(rdP(src, (size_t)(r0 + ty + j) * C + c0 + tx, f32));
  __syncthreads();
  #pragma unroll
  for (int j = 0; j < 32; j += 8)
    dst[(size_t)(c0 + ty + j) * R + r0 + tx] = tile[tx][ty + j];
}

// ---------------------------------------------------------------------------
// LDS-staged GEMM, 64x128 (MxN) block tile, BK=64, 4 waves (each 32x64 via
// 2x4 mfma 16x16x32). Smaller tile than m97's 128x128 on purpose: these
// GEMMs are latency-bound (R5: MfmaUtil 7.5%, Occ 15%, 3 blocks/CU), so we
// trade per-wave MFMA density for 2x the block count (6/CU at N=1536,
// 24 KB LDS). XOR-swizzled 16B chunks, same staging contract as R5:
//   LDS[row][c] = global[row][c ^ (row&7)], lane l -> row base+(l>>3),
//   global chunk (l&7)^(l>>3)  (row bases are multiples of 8).
// lda = A row stride. mode 0: C. 1: C+extra. 2: silu(extra)*C.
// ---------------------------------------------------------------------------
#define BK 64
__global__ __launch_bounds__(256) void gemm_kernel(
    const bf16* __restrict__ A, const bf16* __restrict__ Bt,
    bf16* Cout, const bf16* extra, int N, int K, int lda, int mode)
{
  __shared__ alignas(16) bf16 As[64 * BK];    //  8 KB
  __shared__ alignas(16) bf16 Bs[128 * BK];   // 16 KB

  int lane = threadIdx.x & 63;
  int wid  = threadIdx.x >> 6;
  int quad = lane >> 4;
  int l16  = lane & 15;
  int mbase = blockIdx.y * 64;
  int nbase = blockIdx.x * 128;
  int wm = (wid >> 1) * 32;
  int wn = (wid & 1) * 64;

  int srowA  = wid * 16 + (lane >> 3);        // wave stages A rows wid*16..+15
  int srowB  = wid * 32 + (lane >> 3);        // and B rows wid*32..+31
  int schunk = (lane & 7) ^ (lane >> 3);
  const bf16* Ag = A  + (size_t)(mbase + srowA) * lda + schunk * 8;
  const bf16* Bg = Bt + (size_t)(nbase + srowB) * K   + schunk * 8;

  f32x4 acc[2][4] = {};

  for (int k0 = 0; k0 < K; k0 += BK) {
    __syncthreads();
    #pragma unroll
    for (int it = 0; it < 2; ++it)
      gload_lds16(Ag + (size_t)(it * 8) * lda + k0, &As[(wid * 16 + it * 8) * BK]);
    #pragma unroll
    for (int it = 0; it < 4; ++it)
      gload_lds16(Bg + (size_t)(it * 8) * K + k0,   &Bs[(wid * 32 + it * 8) * BK]);
    __syncthreads();

    #pragma unroll
    for (int ko = 0; ko < 2; ++ko) {
      bf16x8 a[2], b[4];
      #pragma unroll
      for (int i = 0; i < 2; ++i) {
        int row = wm + i * 16 + l16;
        int c = (ko * 4 + quad) ^ (l16 & 7);
        a[i] = *reinterpret_cast<const bf16x8*>(&As[row * BK + c * 8]);
      }
      #pragma unroll
      for (int j = 0; j < 4; ++j) {
        int row = wn + j * 16 + l16;
        int c = (ko * 4 + quad) ^ (l16 & 7);
        b[j] = *reinterpret_cast<const bf16x8*>(&Bs[row * BK + c * 8]);
      }
      #pragma unroll
      for (int i = 0; i < 2; ++i)
        #pragma unroll
        for (int j = 0; j < 4; ++j)
          acc[i][j] = __builtin_amdgcn_mfma_f32_16x16x32_bf16(a[i], b[j], acc[i][j], 0, 0, 0);
    }
  }

  #pragma unroll
  for (int i = 0; i < 2; ++i) {
    #pragma unroll
    for (int j = 0; j < 4; ++j) {
      #pragma unroll
      for (int r = 0; r < 4; ++r) {
        int row = mbase + wm + i * 16 + quad * 4 + r;
        int col = nbase + wn + j * 16 + l16;
        size_t idx = (size_t)row * N + col;
        float c = acc[i][j][r];
        if (mode == 1) {
          c += b2f(extra[idx]);
        } else if (mode == 2) {
          float gg = b2f(extra[idx]);
          c *= gg / (1.f + expf(-gg));
        }
        Cout[idx] = f2b(c);
      }
    }
  }
}

// ---------------------------------------------------------------------------
// MFMA sliding-window sigmoid attention over the fused qkv buffer
// (row stride QKV_LD; q at col 0, k at 512+head*128, v at +64).
// msg overwrites the q slot (own rows/cols only).
// ---------------------------------------------------------------------------
#define VT_BYTES 9216   // 64 rows * 144 B  (stride >= 128 B span; R3 fix)
#define PL_BYTES 2304   // P: 16 rows x 72 bf16
__device__ __forceinline__ int vt_addr(int d, int t) {
  return d * 144 + t * 2;
}

__global__ __launch_bounds__(256) void attn_mfma_kernel(bf16* qkv)
{
  __shared__ alignas(16) char lds_raw[4 * (VT_BYTES + PL_BYTES)];
  int lane = threadIdx.x & 63;
  int widx = threadIdx.x >> 6;
  int u    = blockIdx.x * 4 + widx;
  int tile = u >> 3, head = u & 7;
  int rowbase = tile * 16;
  int t0   = rowbase & (T_LEN - 1);
  int l16  = lane & 15, quad = lane >> 4;

  char* wbase = lds_raw + widx * (VT_BYTES + PL_BYTES);
  char* Vl = wbase;
  bf16* Pl = (bf16*)(wbase + VT_BYTES);

  {
    #pragma unroll
    for (int it = 0; it < 6; ++it) {
      int chunk = it * 64 + lane;
      int t  = chunk >> 3;
      int dc = chunk & 7;
      int row = rowbase - 32 + t;
      if (row < 0) row = 0;           // garbage ok: masked by tau=0
      bf16x8 v = *reinterpret_cast<const bf16x8*>(
          qkv + (size_t)row * QKV_LD + 512 + head * 128 + 64 + dc * 8);
      #pragma unroll
      for (int jj = 0; jj < 8; ++jj)
        *(bf16*)(Vl + vt_addr(dc * 8 + jj, t)) = (bf16)(__bf16)v[jj];
    }
    bf16x8 z = {};
    *reinterpret_cast<bf16x8*>(Vl + vt_addr(lane, 48)) = z;
    *reinterpret_cast<bf16x8*>(Vl + vt_addr(lane, 56)) = z;
  }

  bf16x8 aq0, aq1;
  {
    const bf16* qrow = qkv + (size_t)(rowbase + l16) * QKV_LD + head * HD_DIM + quad * 8;
    aq0 = *reinterpret_cast<const bf16x8*>(qrow);
    aq1 = *reinterpret_cast<const bf16x8*>(qrow + 32);
  }

  f32x4 sacc[3] = {};
  #pragma unroll
  for (int jt = 0; jt < 3; ++jt) {
    int tok = rowbase - 32 + jt * 16 + l16;
    if (tok < 0) tok = 0;             // garbage ok: masked
    const bf16* krow = qkv + (size_t)tok * QKV_LD + 512 + head * 128 + quad * 8;
    bf16x8 b0 = *reinterpret_cast<const bf16x8*>(krow);
    bf16x8 b1 = *reinterpret_cast<const bf16x8*>(krow + 32);
    sacc[jt] = __builtin_amdgcn_mfma_f32_16x16x32_bf16(aq0, b0, sacc[jt], 0, 0, 0);
    sacc[jt] = __builtin_amdgcn_mfma_f32_16x16x32_bf16(aq1, b1, sacc[jt], 0, 0, 0);
  }

  #pragma unroll
  for (int jt = 0; jt < 3; ++jt) {
    int j = jt * 16 + l16;
    #pragma unroll
    for (int r = 0; r < 4; ++r) {
      int i = quad * 4 + r;
      bool valid = (j >= i) && (j <= i + 31) && (t0 - 32 + j >= 0);
      float tau = valid ? 1.f / (1.f + expf(-sacc[jt][r] * 0.125f)) : 0.f;
      Pl[i * 72 + j] = f2b(tau);
    }
  }
  {
    #pragma unroll
    for (int r = 0; r < 4; ++r) Pl[(quad * 4 + r) * 72 + 48 + l16] = f2b(0.f);
  }

  __syncthreads();

  bf16x8 ap0 = *reinterpret_cast<const bf16x8*>((char*)Pl + l16 * 144 + quad * 16);
  bf16x8 ap1 = *reinterpret_cast<const bf16x8*>((char*)Pl + l16 * 144 + 64 + quad * 16);

  f32x4 macc[4] = {};
  #pragma unroll
  for (int nt = 0; nt < 4; ++nt) {
    int d = nt * 16 + l16;
    bf16x8 bv0 = *reinterpret_cast<const bf16x8*>(Vl + vt_addr(d, quad * 8));
    bf16x8 bv1 = *reinterpret_cast<const bf16x8*>(Vl + vt_addr(d, 32 + quad * 8));
    macc[nt] = __builtin_amdgcn_mfma_f32_16x16x32_bf16(ap0, bv0, macc[nt], 0, 0, 0);
    macc[nt] = __builtin_amdgcn_mfma_f32_16x16x32_bf16(ap1, bv1, macc[nt], 0, 0, 0);
  }

  #pragma unroll
  for (int nt = 0; nt < 4; ++nt)
    #pragma unroll
    for (int r = 0; r < 4; ++r)
      qkv[(size_t)(rowbase + quad * 4 + r) * QKV_LD + head * HD_DIM + nt * 16 + l16] =
          f2b(macc[nt][r]);
}

// ---------------------------------------------------------------------------
extern "C" void kernel_launch(void* const* d_in, const int* in_sizes, int n_in,
                              void* d_out, int out_size, void* d_ws, size_t ws_size,
                              hipStream_t stream)
{
  const void* x      = d_in[0];
  const void* pre_g  = d_in[1];
  const void* pre_b  = d_in[2];
  const void* wq     = d_in[3];
  const void* wkv    = d_in[4];
  const void* wo     = d_in[5];
  const void* attn_g = d_in[6];
  const void* attn_b = d_in[7];
  const void* freqs  = d_in[8];
  const void* phases = d_in[9];
  const void* amp    = d_in[10];
  const void* w_gate = d_in[11];
  const void* w_val  = d_in[12];
  const void* w_proj = d_in[13];
  const void* ffn_g  = d_in[14];
  const void* ffn_b  = d_in[15];

  char* ws = (char*)d_ws;
  int*  flag  = (int*)(ws + 0);
  bf16* Btqkv = (bf16*)(ws + 512);       // 1536 x 512 (wq rows 0..511, wkv 512..1535)
  bf16* Bto   = (bf16*)(ws + 1573376);   //  512 x 512
  bf16* Btg   = (bf16*)(ws + 2097664);   // 1536 x 512
  bf16* Btv   = (bf16*)(ws + 3670528);   // 1536 x 512
  bf16* Btp   = (bf16*)(ws + 5243392);   //  512 x 1536
  bf16* h     = (bf16*)(ws + 6816256);   // 8192 x 512   (h -> s1 -> y -> u)
  bf16* qkvb  = (bf16*)(ws + 15204864);  // 8192 x 1536  (q|kv; msg in-place; then gb)
  bf16* gb    = qkvb;                    // FFN gate/act reuses qkv region

  detect_kernel<<<1, 64, 0, stream>>>((const unsigned*)x, flag);

  // all weight transposes -> [N x K] bf16, one dispatch
  transpose_all_kernel<<<3328, 256, 0, stream>>>(
      wq, wkv, wo, w_gate, w_val, w_proj,
      Btqkv, Btqkv + 512 * 512, Bto, Btg, Btv, Btp, flag);

  // h = LN(x)
  ln_kernel<<<2048, 256, 0, stream>>>(x, pre_g, pre_b, h, 0,
                                      nullptr, nullptr, nullptr, flag, 1, 0);

  // qkv = h @ [wq|wkv]  (fused, N=1536)
  gemm_kernel<<<dim3(12, 128), 256, 0, stream>>>(h, Btqkv, qkvb, nullptr, 1536, 512, 512, 0);

  // msg = window-attention (in-place over q slot)
  attn_mfma_kernel<<<1024, 256, 0, stream>>>(qkvb);

  // s1 = h + msg @ wo
  gemm_kernel<<<dim3(4, 128),  256, 0, stream>>>(qkvb, Bto, h, h, 512, 512, QKV_LD, 1);

  // y = LN(s1) * (1 + amp*sin(...))
  ln_kernel<<<2048, 256, 0, stream>>>(h, attn_g, attn_b, h, 1,
                                      freqs, phases, amp, flag, 0, 0);

  // g = y @ w_gate ; act = silu(g) * (y @ w_val)
  gemm_kernel<<<dim3(12, 128), 256, 0, stream>>>(h, Btg, gb, nullptr, 1536, 512, 512, 0);
  gemm_kernel<<<dim3(12, 128), 256, 0, stream>>>(h, Btv, gb, gb,      1536, 512, 512, 2);

  // u = y + act @ w_proj
  gemm_kernel<<<dim3(4, 128),  256, 0, stream>>>(gb, Btp, h, h, 512, 1536, QKV_LD, 1);

  // out = LN(u)
  ln_kernel<<<2048, 256, 0, stream>>>(h, ffn_g, ffn_b, d_out, 0,
                                      nullptr, nullptr, nullptr, flag, 0, 1);
}

// Round 7
// 307.592 us; speedup vs baseline: 1.9724x; 1.0570x over previous
//
#include <hip/hip_runtime.h>
#include <hip/hip_bf16.h>
#include <math.h>

// Problem constants
#define T_LEN   4096
#define D_DIM   512
#define H_NUM   8
#define HD_DIM  64
#define W_WIN   32
#define HID_DIM 1536
#define M_ROWS  8192   // B*T
#define QKV_LD  1536   // fused q|kv row stride

typedef __hip_bfloat16 bf16;
typedef __bf16  bf16x8 __attribute__((ext_vector_type(8)));
typedef float   f32x4  __attribute__((ext_vector_type(4)));

__device__ __forceinline__ float b2f(bf16 x) { return __bfloat162float(x); }
__device__ __forceinline__ bf16  f2b(float x){ return __float2bfloat16(x); }

__device__ __forceinline__ float rdP(const void* p, int i, bool f32) {
  return f32 ? ((const float*)p)[i] : b2f(((const bf16*)p)[i]);
}

__device__ __forceinline__ float wave_reduce_sum(float v) {
  #pragma unroll
  for (int off = 32; off; off >>= 1) v += __shfl_xor(v, off, 64);
  return v;
}

// Async global->LDS, 16B per lane; HW writes lds + lane*16 (wave-uniform base).
__device__ __forceinline__ void gload_lds16(const bf16* g, bf16* l) {
  __builtin_amdgcn_global_load_lds(
      (const __attribute__((address_space(1))) unsigned int*)g,
      (__attribute__((address_space(3))) unsigned int*)l, 16, 0, 0);
}

// ---------------------------------------------------------------------------
// Input-dtype detector. flag=1 -> inputs are float32.
// ---------------------------------------------------------------------------
__global__ void detect_kernel(const unsigned* __restrict__ x, int* flag) {
  int lane = threadIdx.x & 63;
  int votes = 0;
  #pragma unroll
  for (int i = 0; i < 4; ++i) {
    unsigned e = (x[lane * 4 + i] >> 7) & 0xffu;
    votes += (e >= 90u && e <= 140u) ? 1 : 0;
  }
  float v = wave_reduce_sum((float)votes);
  if (lane == 0) *flag = (v < 200.f) ? 1 : 0;
}

// ---------------------------------------------------------------------------
// LayerNorm (R2-validated).
// ---------------------------------------------------------------------------
__global__ __launch_bounds__(256) void ln_kernel(
    const void* __restrict__ in, const void* __restrict__ g, const void* __restrict__ bb,
    void* __restrict__ out, int mode,
    const void* __restrict__ freqs, const void* __restrict__ phases,
    const void* __restrict__ amp,
    const int* __restrict__ flag, int in_follows, int out_follows)
{
  bool f32  = (*flag != 0);
  bool inF  = f32 && (in_follows != 0);
  bool outF = f32 && (out_follows != 0);

  int wave = threadIdx.x >> 6;
  int lane = threadIdx.x & 63;
  int row  = blockIdx.x * 4 + wave;

  float x[8];
  if (inF) {
    const float* rp = (const float*)in + (size_t)row * D_DIM + lane * 8;
    float4 v0 = *reinterpret_cast<const float4*>(rp);
    float4 v1 = *reinterpret_cast<const float4*>(rp + 4);
    x[0]=v0.x; x[1]=v0.y; x[2]=v0.z; x[3]=v0.w;
    x[4]=v1.x; x[5]=v1.y; x[6]=v1.z; x[7]=v1.w;
  } else {
    bf16x8 v = *reinterpret_cast<const bf16x8*>(
        (const bf16*)in + (size_t)row * D_DIM + lane * 8);
    #pragma unroll
    for (int i = 0; i < 8; ++i) x[i] = (float)v[i];
  }

  float s = 0.f, s2 = 0.f;
  #pragma unroll
  for (int i = 0; i < 8; ++i) { s += x[i]; s2 += x[i]*x[i]; }
  s  = wave_reduce_sum(s);
  s2 = wave_reduce_sum(s2);
  float mu   = s * (1.f / D_DIM);
  float var  = s2 * (1.f / D_DIM) - mu * mu;
  float rstd = rsqrtf(var + 1e-5f);

  int t = row & (T_LEN - 1);
  float ampf = (mode == 1) ? rdP(amp, 0, f32) : 0.f;

  float o[8];
  #pragma unroll
  for (int i = 0; i < 8; ++i) {
    int d = lane * 8 + i;
    float val = (x[i] - mu) * rstd * rdP(g, d, f32) + rdP(bb, d, f32);
    if (mode == 1) {
      float m = sinf(fmaf((float)t, rdP(freqs, d, f32), rdP(phases, d, f32)));
      val *= (1.f + ampf * m);
    }
    o[i] = val;
  }

  if (outF) {
    float* op = (float*)out + (size_t)row * D_DIM + lane * 8;
    *reinterpret_cast<float4*>(op)     = make_float4(o[0], o[1], o[2], o[3]);
    *reinterpret_cast<float4*>(op + 4) = make_float4(o[4], o[5], o[6], o[7]);
  } else {
    bf16x8 ov;
    #pragma unroll
    for (int i = 0; i < 8; ++i) ov[i] = (__bf16)o[i];
    *reinterpret_cast<bf16x8*>((bf16*)out + (size_t)row * D_DIM + lane * 8) = ov;
  }
}

// ---------------------------------------------------------------------------
// Fused weight transposes: all 6 matrices in one dispatch.
// ---------------------------------------------------------------------------
__global__ __launch_bounds__(256) void transpose_all_kernel(
    const void* s0, const void* s1, const void* s2, const void* s3,
    const void* s4, const void* s5,
    bf16* d0, bf16* d1, bf16* d2, bf16* d3, bf16* d4, bf16* d5,
    const int* __restrict__ flag)
{
  bool f32 = (*flag != 0);
  int bid = blockIdx.x;
  const void* src; bf16* dst; int R, C, lid, tiles_x;
  if      (bid < 256)  { src=s0; dst=d0; R=512;  C=512;  lid=bid;      tiles_x=16; }
  else if (bid < 768)  { src=s1; dst=d1; R=512;  C=1024; lid=bid-256;  tiles_x=32; }
  else if (bid < 1024) { src=s2; dst=d2; R=512;  C=512;  lid=bid-768;  tiles_x=16; }
  else if (bid < 1792) { src=s3; dst=d3; R=512;  C=1536; lid=bid-1024; tiles_x=48; }
  else if (bid < 2560) { src=s4; dst=d4; R=512;  C=1536; lid=bid-1792; tiles_x=48; }
  else                 { src=s5; dst=d5; R=1536; C=512;  lid=bid-2560; tiles_x=16; }

  __shared__ bf16 tile[32][33];
  int tx = threadIdx.x & 31;
  int ty = threadIdx.x >> 5;
  int c0 = (lid % tiles_x) * 32;
  int r0 = (lid / tiles_x) * 32;
  #pragma unroll
  for (int j = 0; j < 32; j += 8)
    tile[ty + j][tx] = f2b(rdP(src, (size_t)(r0 + ty + j) * C + c0 + tx, f32));
  __syncthreads();
  #pragma unroll
  for (int j = 0; j < 32; j += 8)
    dst[(size_t)(c0 + ty + j) * R + r0 + tx] = tile[tx][ty + j];
}

// ---------------------------------------------------------------------------
// LDS-staged GEMM, 64x128 (MxN), BK=64, 4 waves (each 32x64).
// XOR-swizzled 16B chunks: LDS[row][c] = global[row][c ^ (row&7)].
// mode 0: C. 1: C+extra.
// ---------------------------------------------------------------------------
#define BK 64
__global__ __launch_bounds__(256) void gemm_kernel(
    const bf16* __restrict__ A, const bf16* __restrict__ Bt,
    bf16* Cout, const bf16* extra, int N, int K, int lda, int mode)
{
  __shared__ alignas(16) bf16 As[64 * BK];    //  8 KB
  __shared__ alignas(16) bf16 Bs[128 * BK];   // 16 KB

  int lane = threadIdx.x & 63;
  int wid  = threadIdx.x >> 6;
  int quad = lane >> 4;
  int l16  = lane & 15;
  int mbase = blockIdx.y * 64;
  int nbase = blockIdx.x * 128;
  int wm = (wid >> 1) * 32;
  int wn = (wid & 1) * 64;

  int srowA  = wid * 16 + (lane >> 3);
  int srowB  = wid * 32 + (lane >> 3);
  int schunk = (lane & 7) ^ (lane >> 3);
  const bf16* Ag = A  + (size_t)(mbase + srowA) * lda + schunk * 8;
  const bf16* Bg = Bt + (size_t)(nbase + srowB) * K   + schunk * 8;

  f32x4 acc[2][4] = {};

  for (int kit = K / BK; kit > 0; --kit) {
    __syncthreads();
    #pragma unroll
    for (int it = 0; it < 2; ++it)
      gload_lds16(Ag + (size_t)(it * 8) * lda, &As[(wid * 16 + it * 8) * BK]);
    #pragma unroll
    for (int it = 0; it < 4; ++it)
      gload_lds16(Bg + (size_t)(it * 8) * K,   &Bs[(wid * 32 + it * 8) * BK]);
    Ag += BK; Bg += BK;
    __syncthreads();

    #pragma unroll
    for (int ko = 0; ko < 2; ++ko) {
      bf16x8 a[2], b[4];
      #pragma unroll
      for (int i = 0; i < 2; ++i) {
        int row = wm + i * 16 + l16;
        int c = (ko * 4 + quad) ^ (l16 & 7);
        a[i] = *reinterpret_cast<const bf16x8*>(&As[row * BK + c * 8]);
      }
      #pragma unroll
      for (int j = 0; j < 4; ++j) {
        int row = wn + j * 16 + l16;
        int c = (ko * 4 + quad) ^ (l16 & 7);
        b[j] = *reinterpret_cast<const bf16x8*>(&Bs[row * BK + c * 8]);
      }
      #pragma unroll
      for (int i = 0; i < 2; ++i)
        #pragma unroll
        for (int j = 0; j < 4; ++j)
          acc[i][j] = __builtin_amdgcn_mfma_f32_16x16x32_bf16(a[i], b[j], acc[i][j], 0, 0, 0);
    }
  }

  #pragma unroll
  for (int i = 0; i < 2; ++i) {
    #pragma unroll
    for (int j = 0; j < 4; ++j) {
      #pragma unroll
      for (int r = 0; r < 4; ++r) {
        int row = mbase + wm + i * 16 + quad * 4 + r;
        int col = nbase + wn + j * 16 + l16;
        size_t idx = (size_t)row * N + col;
        float c = acc[i][j][r];
        if (mode == 1) c += b2f(extra[idx]);
        Cout[idx] = f2b(c);
      }
    }
  }
}

// ---------------------------------------------------------------------------
// Fused gate+val GEMM: act = silu(A@Wg) * (A@Wv), both [M x N], Bt's [N x K].
// 64x128 tile, stages A once + two B panels; 32 MFMA per k-iter.
// LDS 40 KB -> 4 blocks/CU.
// ---------------------------------------------------------------------------
__global__ __launch_bounds__(256) void gemm_gateval_kernel(
    const bf16* __restrict__ A, const bf16* __restrict__ Btg,
    const bf16* __restrict__ Btv, bf16* __restrict__ Cout,
    int N, int K, int lda)
{
  __shared__ alignas(16) bf16 As [64 * BK];   //  8 KB
  __shared__ alignas(16) bf16 Bgs[128 * BK];  // 16 KB
  __shared__ alignas(16) bf16 Bvs[128 * BK];  // 16 KB

  int lane = threadIdx.x & 63;
  int wid  = threadIdx.x >> 6;
  int quad = lane >> 4;
  int l16  = lane & 15;
  int mbase = blockIdx.y * 64;
  int nbase = blockIdx.x * 128;
  int wm = (wid >> 1) * 32;
  int wn = (wid & 1) * 64;

  int srowA  = wid * 16 + (lane >> 3);
  int srowB  = wid * 32 + (lane >> 3);
  int schunk = (lane & 7) ^ (lane >> 3);
  const bf16* Ag  = A   + (size_t)(mbase + srowA) * lda + schunk * 8;
  const bf16* Bgg = Btg + (size_t)(nbase + srowB) * K   + schunk * 8;
  const bf16* Bvg = Btv + (size_t)(nbase + srowB) * K   + schunk * 8;

  f32x4 accg[2][4] = {};
  f32x4 accv[2][4] = {};

  for (int kit = K / BK; kit > 0; --kit) {
    __syncthreads();
    #pragma unroll
    for (int it = 0; it < 2; ++it)
      gload_lds16(Ag + (size_t)(it * 8) * lda, &As[(wid * 16 + it * 8) * BK]);
    #pragma unroll
    for (int it = 0; it < 4; ++it) {
      gload_lds16(Bgg + (size_t)(it * 8) * K, &Bgs[(wid * 32 + it * 8) * BK]);
      gload_lds16(Bvg + (size_t)(it * 8) * K, &Bvs[(wid * 32 + it * 8) * BK]);
    }
    Ag += BK; Bgg += BK; Bvg += BK;
    __syncthreads();

    #pragma unroll
    for (int ko = 0; ko < 2; ++ko) {
      bf16x8 a[2], bg[4], bv[4];
      #pragma unroll
      for (int i = 0; i < 2; ++i) {
        int row = wm + i * 16 + l16;
        int c = (ko * 4 + quad) ^ (l16 & 7);
        a[i] = *reinterpret_cast<const bf16x8*>(&As[row * BK + c * 8]);
      }
      #pragma unroll
      for (int j = 0; j < 4; ++j) {
        int row = wn + j * 16 + l16;
        int c = (ko * 4 + quad) ^ (l16 & 7);
        bg[j] = *reinterpret_cast<const bf16x8*>(&Bgs[row * BK + c * 8]);
        bv[j] = *reinterpret_cast<const bf16x8*>(&Bvs[row * BK + c * 8]);
      }
      #pragma unroll
      for (int i = 0; i < 2; ++i)
        #pragma unroll
        for (int j = 0; j < 4; ++j) {
          accg[i][j] = __builtin_amdgcn_mfma_f32_16x16x32_bf16(a[i], bg[j], accg[i][j], 0, 0, 0);
          accv[i][j] = __builtin_amdgcn_mfma_f32_16x16x32_bf16(a[i], bv[j], accv[i][j], 0, 0, 0);
        }
    }
  }

  #pragma unroll
  for (int i = 0; i < 2; ++i) {
    #pragma unroll
    for (int j = 0; j < 4; ++j) {
      #pragma unroll
      for (int r = 0; r < 4; ++r) {
        int row = mbase + wm + i * 16 + quad * 4 + r;
        int col = nbase + wn + j * 16 + l16;
        float g = accg[i][j][r];
        float v = accv[i][j][r];
        Cout[(size_t)row * N + col] = f2b(g / (1.f + expf(-g)) * v);
      }
    }
  }
}

// ---------------------------------------------------------------------------
// 64x64-tile GEMM for N=512 outputs (wo, proj): 4 waves of 32x32,
// grid 2x blocks vs 64x128 -> 4 blocks/CU. mode 1: C = P + extra.
// ---------------------------------------------------------------------------
__global__ __launch_bounds__(256) void gemm64_kernel(
    const bf16* __restrict__ A, const bf16* __restrict__ Bt,
    bf16* Cout, const bf16* extra, int N, int K, int lda, int mode)
{
  __shared__ alignas(16) bf16 As[64 * BK];   // 8 KB
  __shared__ alignas(16) bf16 Bs[64 * BK];   // 8 KB

  int lane = threadIdx.x & 63;
  int wid  = threadIdx.x >> 6;
  int quad = lane >> 4;
  int l16  = lane & 15;
  int mbase = blockIdx.y * 64;
  int nbase = blockIdx.x * 64;
  int wm = (wid >> 1) * 32;
  int wn = (wid & 1) * 32;

  int srow   = wid * 16 + (lane >> 3);
  int schunk = (lane & 7) ^ (lane >> 3);
  const bf16* Ag = A  + (size_t)(mbase + srow) * lda + schunk * 8;
  const bf16* Bg = Bt + (size_t)(nbase + srow) * K   + schunk * 8;

  f32x4 acc[2][2] = {};

  for (int kit = K / BK; kit > 0; --kit) {
    __syncthreads();
    #pragma unroll
    for (int it = 0; it < 2; ++it) {
      gload_lds16(Ag + (size_t)(it * 8) * lda, &As[(wid * 16 + it * 8) * BK]);
      gload_lds16(Bg + (size_t)(it * 8) * K,   &Bs[(wid * 16 + it * 8) * BK]);
    }
    Ag += BK; Bg += BK;
    __syncthreads();

    #pragma unroll
    for (int ko = 0; ko < 2; ++ko) {
      bf16x8 a[2], b[2];
      #pragma unroll
      for (int i = 0; i < 2; ++i) {
        int row = wm + i * 16 + l16;
        int c = (ko * 4 + quad) ^ (l16 & 7);
        a[i] = *reinterpret_cast<const bf16x8*>(&As[row * BK + c * 8]);
        row = wn + i * 16 + l16;
        b[i] = *reinterpret_cast<const bf16x8*>(&Bs[row * BK + c * 8]);
      }
      #pragma unroll
      for (int i = 0; i < 2; ++i)
        #pragma unroll
        for (int j = 0; j < 2; ++j)
          acc[i][j] = __builtin_amdgcn_mfma_f32_16x16x32_bf16(a[i], b[j], acc[i][j], 0, 0, 0);
    }
  }

  #pragma unroll
  for (int i = 0; i < 2; ++i) {
    #pragma unroll
    for (int j = 0; j < 2; ++j) {
      #pragma unroll
      for (int r = 0; r < 4; ++r) {
        int row = mbase + wm + i * 16 + quad * 4 + r;
        int col = nbase + wn + j * 16 + l16;
        size_t idx = (size_t)row * N + col;
        float c = acc[i][j][r];
        if (mode == 1) c += b2f(extra[idx]);
        Cout[idx] = f2b(c);
      }
    }
  }
}

// ---------------------------------------------------------------------------
// MFMA sliding-window sigmoid attention over the fused qkv buffer.
// ---------------------------------------------------------------------------
#define VT_BYTES 9216   // 64 rows * 144 B
#define PL_BYTES 2304   // P: 16 rows x 72 bf16
__device__ __forceinline__ int vt_addr(int d, int t) {
  return d * 144 + t * 2;
}

__global__ __launch_bounds__(256) void attn_mfma_kernel(bf16* qkv)
{
  __shared__ alignas(16) char lds_raw[4 * (VT_BYTES + PL_BYTES)];
  int lane = threadIdx.x & 63;
  int widx = threadIdx.x >> 6;
  int u    = blockIdx.x * 4 + widx;
  int tile = u >> 3, head = u & 7;
  int rowbase = tile * 16;
  int t0   = rowbase & (T_LEN - 1);
  int l16  = lane & 15, quad = lane >> 4;

  char* wbase = lds_raw + widx * (VT_BYTES + PL_BYTES);
  char* Vl = wbase;
  bf16* Pl = (bf16*)(wbase + VT_BYTES);

  {
    #pragma unroll
    for (int it = 0; it < 6; ++it) {
      int chunk = it * 64 + lane;
      int t  = chunk >> 3;
      int dc = chunk & 7;
      int row = rowbase - 32 + t;
      if (row < 0) row = 0;           // garbage ok: masked by tau=0
      bf16x8 v = *reinterpret_cast<const bf16x8*>(
          qkv + (size_t)row * QKV_LD + 512 + head * 128 + 64 + dc * 8);
      #pragma unroll
      for (int jj = 0; jj < 8; ++jj)
        *(bf16*)(Vl + vt_addr(dc * 8 + jj, t)) = (bf16)(__bf16)v[jj];
    }
    bf16x8 z = {};
    *reinterpret_cast<bf16x8*>(Vl + vt_addr(lane, 48)) = z;
    *reinterpret_cast<bf16x8*>(Vl + vt_addr(lane, 56)) = z;
  }

  bf16x8 aq0, aq1;
  {
    const bf16* qrow = qkv + (size_t)(rowbase + l16) * QKV_LD + head * HD_DIM + quad * 8;
    aq0 = *reinterpret_cast<const bf16x8*>(qrow);
    aq1 = *reinterpret_cast<const bf16x8*>(qrow + 32);
  }

  f32x4 sacc[3] = {};
  #pragma unroll
  for (int jt = 0; jt < 3; ++jt) {
    int tok = rowbase - 32 + jt * 16 + l16;
    if (tok < 0) tok = 0;             // garbage ok: masked
    const bf16* krow = qkv + (size_t)tok * QKV_LD + 512 + head * 128 + quad * 8;
    bf16x8 b0 = *reinterpret_cast<const bf16x8*>(krow);
    bf16x8 b1 = *reinterpret_cast<const bf16x8*>(krow + 32);
    sacc[jt] = __builtin_amdgcn_mfma_f32_16x16x32_bf16(aq0, b0, sacc[jt], 0, 0, 0);
    sacc[jt] = __builtin_amdgcn_mfma_f32_16x16x32_bf16(aq1, b1, sacc[jt], 0, 0, 0);
  }

  #pragma unroll
  for (int jt = 0; jt < 3; ++jt) {
    int j = jt * 16 + l16;
    #pragma unroll
    for (int r = 0; r < 4; ++r) {
      int i = quad * 4 + r;
      bool valid = (j >= i) && (j <= i + 31) && (t0 - 32 + j >= 0);
      float tau = valid ? 1.f / (1.f + expf(-sacc[jt][r] * 0.125f)) : 0.f;
      Pl[i * 72 + j] = f2b(tau);
    }
  }
  {
    #pragma unroll
    for (int r = 0; r < 4; ++r) Pl[(quad * 4 + r) * 72 + 48 + l16] = f2b(0.f);
  }

  __syncthreads();

  bf16x8 ap0 = *reinterpret_cast<const bf16x8*>((char*)Pl + l16 * 144 + quad * 16);
  bf16x8 ap1 = *reinterpret_cast<const bf16x8*>((char*)Pl + l16 * 144 + 64 + quad * 16);

  f32x4 macc[4] = {};
  #pragma unroll
  for (int nt = 0; nt < 4; ++nt) {
    int d = nt * 16 + l16;
    bf16x8 bv0 = *reinterpret_cast<const bf16x8*>(Vl + vt_addr(d, quad * 8));
    bf16x8 bv1 = *reinterpret_cast<const bf16x8*>(Vl + vt_addr(d, 32 + quad * 8));
    macc[nt] = __builtin_amdgcn_mfma_f32_16x16x32_bf16(ap0, bv0, macc[nt], 0, 0, 0);
    macc[nt] = __builtin_amdgcn_mfma_f32_16x16x32_bf16(ap1, bv1, macc[nt], 0, 0, 0);
  }

  #pragma unroll
  for (int nt = 0; nt < 4; ++nt)
    #pragma unroll
    for (int r = 0; r < 4; ++r)
      qkv[(size_t)(rowbase + quad * 4 + r) * QKV_LD + head * HD_DIM + nt * 16 + l16] =
          f2b(macc[nt][r]);
}

// ---------------------------------------------------------------------------
extern "C" void kernel_launch(void* const* d_in, const int* in_sizes, int n_in,
                              void* d_out, int out_size, void* d_ws, size_t ws_size,
                              hipStream_t stream)
{
  const void* x      = d_in[0];
  const void* pre_g  = d_in[1];
  const void* pre_b  = d_in[2];
  const void* wq     = d_in[3];
  const void* wkv    = d_in[4];
  const void* wo     = d_in[5];
  const void* attn_g = d_in[6];
  const void* attn_b = d_in[7];
  const void* freqs  = d_in[8];
  const void* phases = d_in[9];
  const void* amp    = d_in[10];
  const void* w_gate = d_in[11];
  const void* w_val  = d_in[12];
  const void* w_proj = d_in[13];
  const void* ffn_g  = d_in[14];
  const void* ffn_b  = d_in[15];

  char* ws = (char*)d_ws;
  int*  flag  = (int*)(ws + 0);
  bf16* Btqkv = (bf16*)(ws + 512);       // 1536 x 512
  bf16* Bto   = (bf16*)(ws + 1573376);   //  512 x 512
  bf16* Btg   = (bf16*)(ws + 2097664);   // 1536 x 512
  bf16* Btv   = (bf16*)(ws + 3670528);   // 1536 x 512
  bf16* Btp   = (bf16*)(ws + 5243392);   //  512 x 1536
  bf16* h     = (bf16*)(ws + 6816256);   // 8192 x 512   (h -> s1 -> y -> u)
  bf16* qkvb  = (bf16*)(ws + 15204864);  // 8192 x 1536  (q|kv; msg in-place; then act)
  bf16* gb    = qkvb;                    // FFN act reuses qkv region

  detect_kernel<<<1, 64, 0, stream>>>((const unsigned*)x, flag);

  transpose_all_kernel<<<3328, 256, 0, stream>>>(
      wq, wkv, wo, w_gate, w_val, w_proj,
      Btqkv, Btqkv + 512 * 512, Bto, Btg, Btv, Btp, flag);

  // h = LN(x)
  ln_kernel<<<2048, 256, 0, stream>>>(x, pre_g, pre_b, h, 0,
                                      nullptr, nullptr, nullptr, flag, 1, 0);

  // qkv = h @ [wq|wkv]  (fused, N=1536)
  gemm_kernel<<<dim3(12, 128), 256, 0, stream>>>(h, Btqkv, qkvb, nullptr, 1536, 512, 512, 0);

  // msg = window-attention (in-place over q slot)
  attn_mfma_kernel<<<1024, 256, 0, stream>>>(qkvb);

  // s1 = h + msg @ wo
  gemm64_kernel<<<dim3(8, 128), 256, 0, stream>>>(qkvb, Bto, h, h, 512, 512, QKV_LD, 1);

  // y = LN(s1) * (1 + amp*sin(...))
  ln_kernel<<<2048, 256, 0, stream>>>(h, attn_g, attn_b, h, 1,
                                      freqs, phases, amp, flag, 0, 0);

  // act = silu(y @ w_gate) * (y @ w_val)  (fused, one dispatch)
  gemm_gateval_kernel<<<dim3(12, 128), 256, 0, stream>>>(h, Btg, Btv, gb, 1536, 512, 512);

  // u = y + act @ w_proj
  gemm64_kernel<<<dim3(8, 128), 256, 0, stream>>>(gb, Btp, h, h, 512, 1536, QKV_LD, 1);

  // out = LN(u)
  ln_kernel<<<2048, 256, 0, stream>>>(h, ffn_g, ffn_b, d_out, 0,
                                      nullptr, nullptr, nullptr, flag, 0, 1);
}

// Round 8
// 289.383 us; speedup vs baseline: 2.0965x; 1.0629x over previous
//
#include <hip/hip_runtime.h>
#include <hip/hip_bf16.h>
#include <math.h>

// Problem constants
#define T_LEN   4096
#define D_DIM   512
#define H_NUM   8
#define HD_DIM  64
#define W_WIN   32
#define HID_DIM 1536
#define M_ROWS  8192   // B*T
#define QKV_LD  1536   // fused q|kv row stride

typedef __hip_bfloat16 bf16;
typedef __bf16  bf16x8 __attribute__((ext_vector_type(8)));
typedef float   f32x4  __attribute__((ext_vector_type(4)));

__device__ __forceinline__ float b2f(bf16 x) { return __bfloat162float(x); }
__device__ __forceinline__ bf16  f2b(float x){ return __float2bfloat16(x); }

__device__ __forceinline__ float rdP(const void* p, int i, bool f32) {
  return f32 ? ((const float*)p)[i] : b2f(((const bf16*)p)[i]);
}

__device__ __forceinline__ float wave_reduce_sum(float v) {
  #pragma unroll
  for (int off = 32; off; off >>= 1) v += __shfl_xor(v, off, 64);
  return v;
}

// Wave-parallel input-dtype detection over the same fixed 256 dwords of x.
// Deterministic -> every wave/block computes the identical answer; no
// cross-block communication needed. true -> inputs are float32.
__device__ __forceinline__ bool detect_f32(const unsigned* __restrict__ x) {
  int lane = threadIdx.x & 63;
  int votes = 0;
  #pragma unroll
  for (int i = 0; i < 4; ++i) {
    unsigned e = (x[lane * 4 + i] >> 7) & 0xffu;   // exponent of low half
    votes += (e >= 90u && e <= 140u) ? 1 : 0;
  }
  float v = wave_reduce_sum((float)votes);         // all lanes get the sum
  return v < 200.f;
}

// Async global->LDS, 16B per lane; HW writes lds + lane*16 (wave-uniform base).
__device__ __forceinline__ void gload_lds16(const bf16* g, bf16* l) {
  __builtin_amdgcn_global_load_lds(
      (const __attribute__((address_space(1))) unsigned int*)g,
      (__attribute__((address_space(3))) unsigned int*)l, 16, 0, 0);
}

// XCD-aware 1-D block swizzle: lid%8 selects the XCD (round-robin dispatch);
// all bx-tiles sharing one by land on the SAME XCD so the A row-panel is
// fetched into exactly one L2. Requires gy % 8 == 0.
__device__ __forceinline__ void swizzle_xy(int gx, int& bx, int& by) {
  int lid = blockIdx.x;
  int sub = lid & 7;
  int grp = lid >> 3;
  bx = grp % gx;
  by = (grp / gx) * 8 + sub;
}

// ---------------------------------------------------------------------------
// LayerNorm (R2-validated; self-detecting dtype).
// ---------------------------------------------------------------------------
__global__ __launch_bounds__(256) void ln_kernel(
    const void* __restrict__ in, const void* __restrict__ g, const void* __restrict__ bb,
    void* __restrict__ out, int mode,
    const void* __restrict__ freqs, const void* __restrict__ phases,
    const void* __restrict__ amp,
    const unsigned* __restrict__ xdet, int in_follows, int out_follows)
{
  bool f32  = detect_f32(xdet);
  bool inF  = f32 && (in_follows != 0);
  bool outF = f32 && (out_follows != 0);

  int wave = threadIdx.x >> 6;
  int lane = threadIdx.x & 63;
  int row  = blockIdx.x * 4 + wave;

  float x[8];
  if (inF) {
    const float* rp = (const float*)in + (size_t)row * D_DIM + lane * 8;
    float4 v0 = *reinterpret_cast<const float4*>(rp);
    float4 v1 = *reinterpret_cast<const float4*>(rp + 4);
    x[0]=v0.x; x[1]=v0.y; x[2]=v0.z; x[3]=v0.w;
    x[4]=v1.x; x[5]=v1.y; x[6]=v1.z; x[7]=v1.w;
  } else {
    bf16x8 v = *reinterpret_cast<const bf16x8*>(
        (const bf16*)in + (size_t)row * D_DIM + lane * 8);
    #pragma unroll
    for (int i = 0; i < 8; ++i) x[i] = (float)v[i];
  }

  float s = 0.f, s2 = 0.f;
  #pragma unroll
  for (int i = 0; i < 8; ++i) { s += x[i]; s2 += x[i]*x[i]; }
  s  = wave_reduce_sum(s);
  s2 = wave_reduce_sum(s2);
  float mu   = s * (1.f / D_DIM);
  float var  = s2 * (1.f / D_DIM) - mu * mu;
  float rstd = rsqrtf(var + 1e-5f);

  int t = row & (T_LEN - 1);
  float ampf = (mode == 1) ? rdP(amp, 0, f32) : 0.f;

  float o[8];
  #pragma unroll
  for (int i = 0; i < 8; ++i) {
    int d = lane * 8 + i;
    float val = (x[i] - mu) * rstd * rdP(g, d, f32) + rdP(bb, d, f32);
    if (mode == 1) {
      float m = sinf(fmaf((float)t, rdP(freqs, d, f32), rdP(phases, d, f32)));
      val *= (1.f + ampf * m);
    }
    o[i] = val;
  }

  if (outF) {
    float* op = (float*)out + (size_t)row * D_DIM + lane * 8;
    *reinterpret_cast<float4*>(op)     = make_float4(o[0], o[1], o[2], o[3]);
    *reinterpret_cast<float4*>(op + 4) = make_float4(o[4], o[5], o[6], o[7]);
  } else {
    bf16x8 ov;
    #pragma unroll
    for (int i = 0; i < 8; ++i) ov[i] = (__bf16)o[i];
    *reinterpret_cast<bf16x8*>((bf16*)out + (size_t)row * D_DIM + lane * 8) = ov;
  }
}

// ---------------------------------------------------------------------------
// Fused weight transposes (self-detecting dtype).
// ---------------------------------------------------------------------------
__global__ __launch_bounds__(256) void transpose_all_kernel(
    const void* s0, const void* s1, const void* s2, const void* s3,
    const void* s4, const void* s5,
    bf16* d0, bf16* d1, bf16* d2, bf16* d3, bf16* d4, bf16* d5,
    const unsigned* __restrict__ xdet)
{
  bool f32 = detect_f32(xdet);
  int bid = blockIdx.x;
  const void* src; bf16* dst; int R, C, lid, tiles_x;
  if      (bid < 256)  { src=s0; dst=d0; R=512;  C=512;  lid=bid;      tiles_x=16; }
  else if (bid < 768)  { src=s1; dst=d1; R=512;  C=1024; lid=bid-256;  tiles_x=32; }
  else if (bid < 1024) { src=s2; dst=d2; R=512;  C=512;  lid=bid-768;  tiles_x=16; }
  else if (bid < 1792) { src=s3; dst=d3; R=512;  C=1536; lid=bid-1024; tiles_x=48; }
  else if (bid < 2560) { src=s4; dst=d4; R=512;  C=1536; lid=bid-1792; tiles_x=48; }
  else                 { src=s5; dst=d5; R=1536; C=512;  lid=bid-2560; tiles_x=16; }

  __shared__ bf16 tile[32][33];
  int tx = threadIdx.x & 31;
  int ty = threadIdx.x >> 5;
  int c0 = (lid % tiles_x) * 32;
  int r0 = (lid / tiles_x) * 32;
  #pragma unroll
  for (int j = 0; j < 32; j += 8)
    tile[ty + j][tx] = f2b(rdP(src, (size_t)(r0 + ty + j) * C + c0 + tx, f32));
  __syncthreads();
  #pragma unroll
  for (int j = 0; j < 32; j += 8)
    dst[(size_t)(c0 + ty + j) * R + r0 + tx] = tile[tx][ty + j];
}

// ---------------------------------------------------------------------------
// 64x64-tile LDS-staged GEMM, BK=64, 4 waves of 32x32. 16 KB LDS ->
// 8 blocks/CU (wave-capped). XOR-swizzled 16B chunks:
//   LDS[row][c] = global[row][c ^ (row&7)]; staging lane l -> row base+(l>>3),
//   global chunk (l&7)^(l>>3). 1-D grid + XCD swizzle (gx N-tiles).
// mode 0: C. 1: C+extra.
// ---------------------------------------------------------------------------
#define BK 64
__global__ __launch_bounds__(256) void gemm64_kernel(
    const bf16* __restrict__ A, const bf16* __restrict__ Bt,
    bf16* Cout, const bf16* extra, int N, int K, int lda, int mode, int gx)
{
  __shared__ alignas(16) bf16 As[64 * BK];   // 8 KB
  __shared__ alignas(16) bf16 Bs[64 * BK];   // 8 KB

  int bx, by; swizzle_xy(gx, bx, by);
  int lane = threadIdx.x & 63;
  int wid  = threadIdx.x >> 6;
  int quad = lane >> 4;
  int l16  = lane & 15;
  int mbase = by * 64;
  int nbase = bx * 64;
  int wm = (wid >> 1) * 32;
  int wn = (wid & 1) * 32;

  int srow   = wid * 16 + (lane >> 3);
  int schunk = (lane & 7) ^ (lane >> 3);
  const bf16* Ag = A  + (size_t)(mbase + srow) * lda + schunk * 8;
  const bf16* Bg = Bt + (size_t)(nbase + srow) * K   + schunk * 8;

  f32x4 acc[2][2] = {};

  for (int kit = K / BK; kit > 0; --kit) {
    __syncthreads();
    #pragma unroll
    for (int it = 0; it < 2; ++it) {
      gload_lds16(Ag + (size_t)(it * 8) * lda, &As[(wid * 16 + it * 8) * BK]);
      gload_lds16(Bg + (size_t)(it * 8) * K,   &Bs[(wid * 16 + it * 8) * BK]);
    }
    Ag += BK; Bg += BK;
    __syncthreads();

    #pragma unroll
    for (int ko = 0; ko < 2; ++ko) {
      bf16x8 a[2], b[2];
      #pragma unroll
      for (int i = 0; i < 2; ++i) {
        int c = (ko * 4 + quad) ^ (l16 & 7);
        a[i] = *reinterpret_cast<const bf16x8*>(&As[(wm + i * 16 + l16) * BK + c * 8]);
        b[i] = *reinterpret_cast<const bf16x8*>(&Bs[(wn + i * 16 + l16) * BK + c * 8]);
      }
      #pragma unroll
      for (int i = 0; i < 2; ++i)
        #pragma unroll
        for (int j = 0; j < 2; ++j)
          acc[i][j] = __builtin_amdgcn_mfma_f32_16x16x32_bf16(a[i], b[j], acc[i][j], 0, 0, 0);
    }
  }

  #pragma unroll
  for (int i = 0; i < 2; ++i) {
    #pragma unroll
    for (int j = 0; j < 2; ++j) {
      #pragma unroll
      for (int r = 0; r < 4; ++r) {
        int row = mbase + wm + i * 16 + quad * 4 + r;
        int col = nbase + wn + j * 16 + l16;
        size_t idx = (size_t)row * N + col;
        float c = acc[i][j][r];
        if (mode == 1) c += b2f(extra[idx]);
        Cout[idx] = f2b(c);
      }
    }
  }
}

// ---------------------------------------------------------------------------
// Fused gate+val GEMM, 64x64 tile: act = silu(A@Wg)*(A@Wv). Stages A once +
// two B panels (24 KB LDS -> ~6 blocks/CU); 16 MFMA per k-iter per wave.
// ---------------------------------------------------------------------------
__global__ __launch_bounds__(256) void gemm_gateval_kernel(
    const bf16* __restrict__ A, const bf16* __restrict__ Btg,
    const bf16* __restrict__ Btv, bf16* __restrict__ Cout,
    int N, int K, int lda, int gx)
{
  __shared__ alignas(16) bf16 As [64 * BK];  // 8 KB
  __shared__ alignas(16) bf16 Bgs[64 * BK];  // 8 KB
  __shared__ alignas(16) bf16 Bvs[64 * BK];  // 8 KB

  int bx, by; swizzle_xy(gx, bx, by);
  int lane = threadIdx.x & 63;
  int wid  = threadIdx.x >> 6;
  int quad = lane >> 4;
  int l16  = lane & 15;
  int mbase = by * 64;
  int nbase = bx * 64;
  int wm = (wid >> 1) * 32;
  int wn = (wid & 1) * 32;

  int srow   = wid * 16 + (lane >> 3);
  int schunk = (lane & 7) ^ (lane >> 3);
  const bf16* Ag  = A   + (size_t)(mbase + srow) * lda + schunk * 8;
  const bf16* Bgg = Btg + (size_t)(nbase + srow) * K   + schunk * 8;
  const bf16* Bvg = Btv + (size_t)(nbase + srow) * K   + schunk * 8;

  f32x4 accg[2][2] = {};
  f32x4 accv[2][2] = {};

  for (int kit = K / BK; kit > 0; --kit) {
    __syncthreads();
    #pragma unroll
    for (int it = 0; it < 2; ++it) {
      gload_lds16(Ag  + (size_t)(it * 8) * lda, &As [(wid * 16 + it * 8) * BK]);
      gload_lds16(Bgg + (size_t)(it * 8) * K,   &Bgs[(wid * 16 + it * 8) * BK]);
      gload_lds16(Bvg + (size_t)(it * 8) * K,   &Bvs[(wid * 16 + it * 8) * BK]);
    }
    Ag += BK; Bgg += BK; Bvg += BK;
    __syncthreads();

    #pragma unroll
    for (int ko = 0; ko < 2; ++ko) {
      bf16x8 a[2], bg[2], bv[2];
      #pragma unroll
      for (int i = 0; i < 2; ++i) {
        int c = (ko * 4 + quad) ^ (l16 & 7);
        a[i]  = *reinterpret_cast<const bf16x8*>(&As [(wm + i * 16 + l16) * BK + c * 8]);
        bg[i] = *reinterpret_cast<const bf16x8*>(&Bgs[(wn + i * 16 + l16) * BK + c * 8]);
        bv[i] = *reinterpret_cast<const bf16x8*>(&Bvs[(wn + i * 16 + l16) * BK + c * 8]);
      }
      #pragma unroll
      for (int i = 0; i < 2; ++i)
        #pragma unroll
        for (int j = 0; j < 2; ++j) {
          accg[i][j] = __builtin_amdgcn_mfma_f32_16x16x32_bf16(a[i], bg[j], accg[i][j], 0, 0, 0);
          accv[i][j] = __builtin_amdgcn_mfma_f32_16x16x32_bf16(a[i], bv[j], accv[i][j], 0, 0, 0);
        }
    }
  }

  #pragma unroll
  for (int i = 0; i < 2; ++i) {
    #pragma unroll
    for (int j = 0; j < 2; ++j) {
      #pragma unroll
      for (int r = 0; r < 4; ++r) {
        int row = mbase + wm + i * 16 + quad * 4 + r;
        int col = nbase + wn + j * 16 + l16;
        float g = accg[i][j][r];
        float v = accv[i][j][r];
        Cout[(size_t)row * N + col] = f2b(g / (1.f + expf(-g)) * v);
      }
    }
  }
}

// ---------------------------------------------------------------------------
// MFMA sliding-window sigmoid attention over the fused qkv buffer.
// ---------------------------------------------------------------------------
#define VT_BYTES 9216   // 64 rows * 144 B
#define PL_BYTES 2304   // P: 16 rows x 72 bf16
__device__ __forceinline__ int vt_addr(int d, int t) {
  return d * 144 + t * 2;
}

__global__ __launch_bounds__(256) void attn_mfma_kernel(bf16* qkv)
{
  __shared__ alignas(16) char lds_raw[4 * (VT_BYTES + PL_BYTES)];
  int lane = threadIdx.x & 63;
  int widx = threadIdx.x >> 6;
  int u    = blockIdx.x * 4 + widx;
  int tile = u >> 3, head = u & 7;
  int rowbase = tile * 16;
  int t0   = rowbase & (T_LEN - 1);
  int l16  = lane & 15, quad = lane >> 4;

  char* wbase = lds_raw + widx * (VT_BYTES + PL_BYTES);
  char* Vl = wbase;
  bf16* Pl = (bf16*)(wbase + VT_BYTES);

  {
    #pragma unroll
    for (int it = 0; it < 6; ++it) {
      int chunk = it * 64 + lane;
      int t  = chunk >> 3;
      int dc = chunk & 7;
      int row = rowbase - 32 + t;
      if (row < 0) row = 0;           // garbage ok: masked by tau=0
      bf16x8 v = *reinterpret_cast<const bf16x8*>(
          qkv + (size_t)row * QKV_LD + 512 + head * 128 + 64 + dc * 8);
      #pragma unroll
      for (int jj = 0; jj < 8; ++jj)
        *(bf16*)(Vl + vt_addr(dc * 8 + jj, t)) = (bf16)(__bf16)v[jj];
    }
    bf16x8 z = {};
    *reinterpret_cast<bf16x8*>(Vl + vt_addr(lane, 48)) = z;
    *reinterpret_cast<bf16x8*>(Vl + vt_addr(lane, 56)) = z;
  }

  bf16x8 aq0, aq1;
  {
    const bf16* qrow = qkv + (size_t)(rowbase + l16) * QKV_LD + head * HD_DIM + quad * 8;
    aq0 = *reinterpret_cast<const bf16x8*>(qrow);
    aq1 = *reinterpret_cast<const bf16x8*>(qrow + 32);
  }

  f32x4 sacc[3] = {};
  #pragma unroll
  for (int jt = 0; jt < 3; ++jt) {
    int tok = rowbase - 32 + jt * 16 + l16;
    if (tok < 0) tok = 0;             // garbage ok: masked
    const bf16* krow = qkv + (size_t)tok * QKV_LD + 512 + head * 128 + quad * 8;
    bf16x8 b0 = *reinterpret_cast<const bf16x8*>(krow);
    bf16x8 b1 = *reinterpret_cast<const bf16x8*>(krow + 32);
    sacc[jt] = __builtin_amdgcn_mfma_f32_16x16x32_bf16(aq0, b0, sacc[jt], 0, 0, 0);
    sacc[jt] = __builtin_amdgcn_mfma_f32_16x16x32_bf16(aq1, b1, sacc[jt], 0, 0, 0);
  }

  #pragma unroll
  for (int jt = 0; jt < 3; ++jt) {
    int j = jt * 16 + l16;
    #pragma unroll
    for (int r = 0; r < 4; ++r) {
      int i = quad * 4 + r;
      bool valid = (j >= i) && (j <= i + 31) && (t0 - 32 + j >= 0);
      float tau = valid ? 1.f / (1.f + expf(-sacc[jt][r] * 0.125f)) : 0.f;
      Pl[i * 72 + j] = f2b(tau);
    }
  }
  {
    #pragma unroll
    for (int r = 0; r < 4; ++r) Pl[(quad * 4 + r) * 72 + 48 + l16] = f2b(0.f);
  }

  __syncthreads();

  bf16x8 ap0 = *reinterpret_cast<const bf16x8*>((char*)Pl + l16 * 144 + quad * 16);
  bf16x8 ap1 = *reinterpret_cast<const bf16x8*>((char*)Pl + l16 * 144 + 64 + quad * 16);

  f32x4 macc[4] = {};
  #pragma unroll
  for (int nt = 0; nt < 4; ++nt) {
    int d = nt * 16 + l16;
    bf16x8 bv0 = *reinterpret_cast<const bf16x8*>(Vl + vt_addr(d, quad * 8));
    bf16x8 bv1 = *reinterpret_cast<const bf16x8*>(Vl + vt_addr(d, 32 + quad * 8));
    macc[nt] = __builtin_amdgcn_mfma_f32_16x16x32_bf16(ap0, bv0, macc[nt], 0, 0, 0);
    macc[nt] = __builtin_amdgcn_mfma_f32_16x16x32_bf16(ap1, bv1, macc[nt], 0, 0, 0);
  }

  #pragma unroll
  for (int nt = 0; nt < 4; ++nt)
    #pragma unroll
    for (int r = 0; r < 4; ++r)
      qkv[(size_t)(rowbase + quad * 4 + r) * QKV_LD + head * HD_DIM + nt * 16 + l16] =
          f2b(macc[nt][r]);
}

// ---------------------------------------------------------------------------
extern "C" void kernel_launch(void* const* d_in, const int* in_sizes, int n_in,
                              void* d_out, int out_size, void* d_ws, size_t ws_size,
                              hipStream_t stream)
{
  const void* x      = d_in[0];
  const void* pre_g  = d_in[1];
  const void* pre_b  = d_in[2];
  const void* wq     = d_in[3];
  const void* wkv    = d_in[4];
  const void* wo     = d_in[5];
  const void* attn_g = d_in[6];
  const void* attn_b = d_in[7];
  const void* freqs  = d_in[8];
  const void* phases = d_in[9];
  const void* amp    = d_in[10];
  const void* w_gate = d_in[11];
  const void* w_val  = d_in[12];
  const void* w_proj = d_in[13];
  const void* ffn_g  = d_in[14];
  const void* ffn_b  = d_in[15];
  const unsigned* xdet = (const unsigned*)x;

  char* ws = (char*)d_ws;
  bf16* Btqkv = (bf16*)(ws + 512);       // 1536 x 512
  bf16* Bto   = (bf16*)(ws + 1573376);   //  512 x 512
  bf16* Btg   = (bf16*)(ws + 2097664);   // 1536 x 512
  bf16* Btv   = (bf16*)(ws + 3670528);   // 1536 x 512
  bf16* Btp   = (bf16*)(ws + 5243392);   //  512 x 1536
  bf16* h     = (bf16*)(ws + 6816256);   // 8192 x 512   (h -> s1 -> y -> u)
  bf16* qkvb  = (bf16*)(ws + 15204864);  // 8192 x 1536  (q|kv; msg in-place; then act)
  bf16* gb    = qkvb;                    // FFN act reuses qkv region

  transpose_all_kernel<<<3328, 256, 0, stream>>>(
      wq, wkv, wo, w_gate, w_val, w_proj,
      Btqkv, Btqkv + 512 * 512, Bto, Btg, Btv, Btp, xdet);

  // h = LN(x)
  ln_kernel<<<2048, 256, 0, stream>>>(x, pre_g, pre_b, h, 0,
                                      nullptr, nullptr, nullptr, xdet, 1, 0);

  // qkv = h @ [wq|wkv]  (fused, N=1536; 24 x 128 tiles)
  gemm64_kernel<<<3072, 256, 0, stream>>>(h, Btqkv, qkvb, nullptr, 1536, 512, 512, 0, 24);

  // msg = window-attention (in-place over q slot)
  attn_mfma_kernel<<<1024, 256, 0, stream>>>(qkvb);

  // s1 = h + msg @ wo  (8 x 128 tiles)
  gemm64_kernel<<<1024, 256, 0, stream>>>(qkvb, Bto, h, h, 512, 512, QKV_LD, 1, 8);

  // y = LN(s1) * (1 + amp*sin(...))
  ln_kernel<<<2048, 256, 0, stream>>>(h, attn_g, attn_b, h, 1,
                                      freqs, phases, amp, xdet, 0, 0);

  // act = silu(y @ w_gate) * (y @ w_val)  (fused; 24 x 128 tiles)
  gemm_gateval_kernel<<<3072, 256, 0, stream>>>(h, Btg, Btv, gb, 1536, 512, 512, 24);

  // u = y + act @ w_proj  (8 x 128 tiles)
  gemm64_kernel<<<1024, 256, 0, stream>>>(gb, Btp, h, h, 512, 1536, QKV_LD, 1, 8);

  // out = LN(u)
  ln_kernel<<<2048, 256, 0, stream>>>(h, ffn_g, ffn_b, d_out, 0,
                                      nullptr, nullptr, nullptr, xdet, 0, 1);
}